// Round 4
// baseline (1369.427 us; speedup 1.0000x reference)
//
#include <hip/hip_runtime.h>
#include <math.h>

// ============================================================================
// SBDD point-cloud network, fp32, bs=8, N_PTS=4096, NB=20, S=1.
// R1: LDS-stage coordinates in kNN merge kernels.
// R2: break survivor-index load serialization (filter pads to x4 sentinels,
//     merge2 4-deep index prefetch, small merges preload 21 idx).
// R3: 128x64 fp32 GEMM tile; kNN insert group-skip; 8-deep prefetch.
// R4: (a) merge2 2 threads/query (each scans 4 chunks, pair-merge via
//     shfl_xor; tie-stable since half0 indices < half1 indices) -> 1.5x
//     occupancy + half the serial stream; (b) k_gem / k_colsum reduction
//     split 4-way (32->512 / 8->32 waves), ordered partial combine.
// ============================================================================

#define NB_K 20
#define BN_EPS 1e-5f

// ---------------------------------------------------------------------------
// Host-side reproduction of np.random.RandomState(seed).permutation(n)
// ---------------------------------------------------------------------------
namespace {
struct MT19937H {
  unsigned mt[624]; int pos;
  void seed(unsigned s) {
    for (int i = 0; i < 624; i++) { mt[i] = s; s = 1812433253u * (s ^ (s >> 30)) + (unsigned)i + 1u; }
    pos = 624;
  }
  unsigned next() {
    if (pos >= 624) {
      for (int i = 0; i < 624; i++) {
        unsigned y = (mt[i] & 0x80000000u) | (mt[(i + 1) % 624] & 0x7fffffffu);
        unsigned v = mt[(i + 397) % 624] ^ (y >> 1);
        if (y & 1u) v ^= 0x9908b0dfu;
        mt[i] = v;
      }
      pos = 0;
    }
    unsigned y = mt[pos++];
    y ^= y >> 11; y ^= (y << 7) & 0x9d2c5680u; y ^= (y << 15) & 0xefc60000u; y ^= y >> 18;
    return y;
  }
  unsigned interval(unsigned mx) {
    if (mx == 0) return 0;
    unsigned mask = mx;
    mask |= mask >> 1; mask |= mask >> 2; mask |= mask >> 4; mask |= mask >> 8; mask |= mask >> 16;
    unsigned v;
    do { v = next() & mask; } while (v > mx);
    return v;
  }
};
struct Pools {
  int p1[1024];
  int p2[256];
  int arr[4096];
  Pools() {
    MT19937H m;
    m.seed(1);
    for (int i = 0; i < 4096; i++) arr[i] = i;
    for (int i = 4095; i >= 1; i--) {
      int j = (int)m.interval((unsigned)i);
      int t = arr[j]; arr[j] = arr[i]; arr[i] = t;
    }
    for (int i = 0; i < 1024; i++) p1[i] = arr[i];
    m.seed(2);
    for (int i = 0; i < 1024; i++) arr[i] = i;
    for (int i = 1023; i >= 1; i--) {
      int j = (int)m.interval((unsigned)i);
      int t = arr[j]; arr[j] = arr[i]; arr[i] = t;
    }
    for (int i = 0; i < 256; i++) p2[i] = arr[i];
  }
};
Pools g_pools;
}

// ---------------------------------------------------------------------------
// Workspace layout (bytes).
// ---------------------------------------------------------------------------
#define OFF_POOL1   (0u)
#define OFF_POOL2   (16u << 10)
#define OFF_DIRN0   (32u << 10)
#define OFF_DIRN1   (36u << 10)
#define OFF_DIRN2   (40u << 10)
#define OFF_DIRN3   (48u << 10)
#define OFF_DIRN4   (56u << 10)
#define OFF_V2      (128u << 10)
#define OFF_V3      (256u << 10)
#define OFF_BN1M    (288u << 10)
#define OFF_BN1R    (292u << 10)
#define OFF_ASUM    (296u << 10)
#define OFF_SCALE1  (304u << 10)
#define OFF_SCALE2  (312u << 10)
#define OFF_HID     (320u << 10)
#define OFF_VLADBN  (352u << 10)
#define OFF_GAT     (384u << 10)
#define OFF_NB      (1u << 20)          // neighbor idx, reused all stages
#define OFF_X1      (4u << 20)          // 16 MB
#define OFF_X2      (20u << 20)         // 16 MB
#define OFF_X3      (36u << 20)         // 8 MB
#define OFF_X4      (44u << 20)         // 8 MB
// knn4096 scratch (X regions free during knn): surv 32MB @X1, cnt 1MB @X3, T0 @X4
#define OFF_KSURV   (OFF_X1)
#define OFF_KCNT    (OFF_X3)
#define OFF_KT0     (OFF_X4)
#define OFF_KPART   (OFF_X1)            // small-level knn partials
#define OFF_ACT0    (OFF_X1)
#define OFF_ACT     (OFF_X1 + (1u << 20))
#define OFF_VLAD    (OFF_X1 + (2u << 20))
#define OFF_PART    (OFF_X1 + (8u << 20))

// ---------------------------------------------------------------------------
// dir normalization: l2norm(dirs, axis=0)
// ---------------------------------------------------------------------------
__global__ void k_dirnorm(const float* __restrict__ d0, const float* __restrict__ d1,
                          const float* __restrict__ d2, const float* __restrict__ d3,
                          const float* __restrict__ d4,
                          float* __restrict__ o0, float* __restrict__ o1,
                          float* __restrict__ o2, float* __restrict__ o3,
                          float* __restrict__ o4) {
  int i = blockIdx.x * 256 + threadIdx.x;
  const float* src; float* dst; int F, c;
  if      (i < 32)   { src = d0; dst = o0; F = 32;   c = i; }
  else if (i < 96)   { src = d1; dst = o1; F = 64;   c = i - 32; }
  else if (i < 224)  { src = d2; dst = o2; F = 128;  c = i - 96; }
  else if (i < 480)  { src = d3; dst = o3; F = 256;  c = i - 224; }
  else if (i < 1504) { src = d4; dst = o4; F = 1024; c = i - 480; }
  else return;
  float a = src[c], b = src[F + c], cc = src[2 * F + c];
  float nr = sqrtf((a * a + b * b) + cc * cc);
  float inv = 1.0f / fmaxf(nr, 1e-12f);
  dst[c] = a * inv; dst[F + c] = b * inv; dst[2 * F + c] = cc * inv;
}

// ---------------------------------------------------------------------------
// kNN. dist via fixed fma chain so all kernels agree bitwise; self-dist == 0.
// ---------------------------------------------------------------------------
__device__ __forceinline__ float dist_fma(float xq, float yq, float zq, float sqq,
                                          float cx, float cy, float cz, float cw) {
  float dot = fmaf(xq, cx, fmaf(yq, cy, zq * cz));
  return fmaf(-2.0f, dot, sqq + cw);
}

// insertion into sorted 21-deep (dist,idx) list; strict < keeps stable
// lowest-index-first tie order identical to jax.lax.top_k.
#define KNN_INSERT(DIST, IDX)                                                 \
  if ((DIST) < kd[20]) {                                                      \
    _Pragma("unroll")                                                         \
    for (int t_ = 20; t_ >= 1; t_--) {                                        \
      bool shift_ = (DIST) < kd[t_ - 1];                                      \
      float nk_ = shift_ ? kd[t_ - 1] : (DIST);                               \
      int   ni_ = shift_ ? ki[t_ - 1] : (IDX);                                \
      bool upd_ = (DIST) < kd[t_];                                            \
      if (upd_) { kd[t_] = nk_; ki[t_] = ni_; }                               \
    }                                                                         \
    if ((DIST) < kd[0]) { kd[0] = (DIST); ki[0] = (IDX); }                    \
  }

// --- knn4096 scheme: sample (exact 21st of first 512) -> filter -> merge ---
template <int N, int SAMPLE>
__global__ void k_knn_sample(const float* __restrict__ v, float* __restrict__ T0) {
  __shared__ float4 tile[SAMPLE];
  int q = blockIdx.x * 64 + threadIdx.x;
  int b = blockIdx.y;
  const float* vb = v + (size_t)b * N * 3;
  for (int j = threadIdx.x; j < SAMPLE; j += 64) {
    float x = vb[j * 3 + 0], y = vb[j * 3 + 1], z = vb[j * 3 + 2];
    tile[j] = make_float4(x, y, z, fmaf(x, x, fmaf(y, y, z * z)));
  }
  __syncthreads();
  float xq = vb[q * 3 + 0], yq = vb[q * 3 + 1], zq = vb[q * 3 + 2];
  float sqq = fmaf(xq, xq, fmaf(yq, yq, zq * zq));
  float kd[21];
#pragma unroll
  for (int t = 0; t < 21; t++) kd[t] = 3.4e38f;
  for (int j = 0; j < SAMPLE; j += 2) {
    float4 c0 = tile[j], c1 = tile[j + 1];
    float d0 = dist_fma(xq, yq, zq, sqq, c0.x, c0.y, c0.z, c0.w);
    float d1 = dist_fma(xq, yq, zq, sqq, c1.x, c1.y, c1.z, c1.w);
    float lo = fminf(d0, d1), hi = fmaxf(d0, d1);
#pragma unroll
    for (int t = 20; t >= 2; --t)
      kd[t] = fminf(fminf(kd[t], fmaxf(kd[t - 1], lo)), fmaxf(kd[t - 2], hi));
    kd[1] = fminf(fminf(kd[1], fmaxf(kd[0], lo)), hi);
    kd[0] = fminf(kd[0], lo);
  }
  T0[(size_t)b * N + q] = kd[20];  // >= global 21st-smallest (sample superset bound)
}

template <int N, int CHUNK, int NCH, int SLOTS>
__global__ void k_knn_filter(const float* __restrict__ v, const float* __restrict__ T0,
                             unsigned short* __restrict__ surv, int* __restrict__ cnt) {
  __shared__ float4 tile[CHUNK];
  int q = blockIdx.x * 64 + threadIdx.x;
  int ch = blockIdx.y;
  int b = blockIdx.z;
  const float* vb = v + (size_t)b * N * 3;
  int cbase = ch * CHUNK;
  for (int j = threadIdx.x; j < CHUNK; j += 64) {
    int g = cbase + j;
    float x = vb[g * 3 + 0], y = vb[g * 3 + 1], z = vb[g * 3 + 2];
    tile[j] = make_float4(x, y, z, fmaf(x, x, fmaf(y, y, z * z)));
  }
  __syncthreads();
  float xq = vb[q * 3 + 0], yq = vb[q * 3 + 1], zq = vb[q * 3 + 2];
  float sqq = fmaf(xq, xq, fmaf(yq, yq, zq * zq));
  float T = T0[(size_t)b * N + q];
  int c = 0;
  unsigned short* sb = surv + ((size_t)b * NCH + ch) * SLOTS * N + q;
  for (int j = 0; j < CHUNK; ++j) {
    float4 cd = tile[j];
    float d = dist_fma(xq, yq, zq, sqq, cd.x, cd.y, cd.z, cd.w);
    if (d <= T && c < SLOTS) {
      sb[(size_t)c * N] = (unsigned short)(cbase + j);
      c++;
    }
  }
  // pad to multiple of 4 with sentinels so merge can run uniform 4-groups
  while (c & 3) { sb[(size_t)c * N] = 0xFFFFu; c++; }
  cnt[((size_t)b * NCH + ch) * N + q] = c;
}

// merge, 2 threads per query: lane pair (2i, 2i+1) handles query i of the
// block; half h scans chunks [h*4, h*4+4) into its own sorted-21 list with
// 8-deep index prefetch + group-skip; then half1's list is sent to half0 via
// shfl_xor and inserted (ascending, strict <) -- tie-stable because half0's
// candidate indices (< N/2) all precede half1's, matching jax.lax.top_k.
template <int N, int NCH, int SLOTS>
__global__ void k_knn_merge2(const float* __restrict__ v, const unsigned short* __restrict__ surv,
                             const int* __restrict__ cnt, int* __restrict__ nb) {
  __shared__ float sx[N], sy[N], sz[N];   // N=4096 -> 48 KB (3 blk/CU)
  int t = threadIdx.x;
  int b = blockIdx.y;
  const float* vb = v + (size_t)b * N * 3;
  for (int j = t; j < N; j += 64) {
    sx[j] = vb[j * 3 + 0];
    sy[j] = vb[j * 3 + 1];
    sz[j] = vb[j * 3 + 2];
  }
  __syncthreads();
  int q = blockIdx.x * 32 + (t >> 1);
  int half = t & 1;
  float xq = sx[q], yq = sy[q], zq = sz[q];
  float sqq = fmaf(xq, xq, fmaf(yq, yq, zq * zq));
  constexpr int HCH = NCH / 2;
  int ch0 = half * HCH;
  // hoist this half's chunk counts (4 independent loads, one latency)
  int cns[HCH];
#pragma unroll
  for (int c = 0; c < HCH; c++) cns[c] = cnt[((size_t)b * NCH + ch0 + c) * N + q];
  float kd[21]; int ki[21];
#pragma unroll
  for (int t2 = 0; t2 < 21; t2++) { kd[t2] = 3.4e38f; ki[t2] = 0; }
#pragma unroll 1
  for (int cc = 0; cc < HCH; cc++) {
    int cn = cns[cc];                    // multiple of 4 (filter pads)
    const unsigned short* sb = surv + ((size_t)b * NCH + ch0 + cc) * SLOTS * N + q;
    int ia0 = 0xFFFF, ia1 = 0xFFFF, ia2 = 0xFFFF, ia3 = 0xFFFF;
    int ib0 = 0xFFFF, ib1 = 0xFFFF, ib2 = 0xFFFF, ib3 = 0xFFFF;
    if (cn > 0) {
      ia0 = sb[0];
      ia1 = sb[(size_t)1 * N];
      ia2 = sb[(size_t)2 * N];
      ia3 = sb[(size_t)3 * N];
    }
    if (cn > 4) {
      ib0 = sb[(size_t)4 * N];
      ib1 = sb[(size_t)5 * N];
      ib2 = sb[(size_t)6 * N];
      ib3 = sb[(size_t)7 * N];
    }
#pragma unroll 1
    for (int s = 0; s < cn; s += 4) {
      int n0 = 0xFFFF, n1 = 0xFFFF, n2 = 0xFFFF, n3 = 0xFFFF;
      if (s + 8 < cn) {
        n0 = sb[(size_t)(s + 8) * N];
        n1 = sb[(size_t)(s + 9) * N];
        n2 = sb[(size_t)(s + 10) * N];
        n3 = sb[(size_t)(s + 11) * N];
      }
      // 4 independent dist computations (LDS reads pipeline)
      float d0, d1, d2, d3;
      {
        int j_ = ia0 & (N - 1);
        float cx = sx[j_], cy = sy[j_], cz = sz[j_];
        float cw = fmaf(cx, cx, fmaf(cy, cy, cz * cz));
        d0 = (ia0 >= N) ? 3.4e38f : dist_fma(xq, yq, zq, sqq, cx, cy, cz, cw);
      }
      {
        int j_ = ia1 & (N - 1);
        float cx = sx[j_], cy = sy[j_], cz = sz[j_];
        float cw = fmaf(cx, cx, fmaf(cy, cy, cz * cz));
        d1 = (ia1 >= N) ? 3.4e38f : dist_fma(xq, yq, zq, sqq, cx, cy, cz, cw);
      }
      {
        int j_ = ia2 & (N - 1);
        float cx = sx[j_], cy = sy[j_], cz = sz[j_];
        float cw = fmaf(cx, cx, fmaf(cy, cy, cz * cz));
        d2 = (ia2 >= N) ? 3.4e38f : dist_fma(xq, yq, zq, sqq, cx, cy, cz, cw);
      }
      {
        int j_ = ia3 & (N - 1);
        float cx = sx[j_], cy = sy[j_], cz = sz[j_];
        float cw = fmaf(cx, cx, fmaf(cy, cy, cz * cz));
        d3 = (ia3 >= N) ? 3.4e38f : dist_fma(xq, yq, zq, sqq, cx, cy, cz, cw);
      }
      // group fast path: skip the whole insertion network if none qualify
      float mind = fminf(fminf(d0, d1), fminf(d2, d3));
      if (mind < kd[20]) {
        KNN_INSERT(d0, ia0);
        KNN_INSERT(d1, ia1);
        KNN_INSERT(d2, ia2);
        KNN_INSERT(d3, ia3);
      }
      ia0 = ib0; ia1 = ib1; ia2 = ib2; ia3 = ib3;
      ib0 = n0;  ib1 = n1;  ib2 = n2;  ib3 = n3;
    }
  }
  // pairwise merge: exchange lists, half0 inserts half1's ascending elements
  float bd[21]; int bi[21];
#pragma unroll
  for (int s = 0; s < 21; s++) {
    bd[s] = __shfl_xor(kd[s], 1);
    bi[s] = __shfl_xor(ki[s], 1);
  }
  if (half == 0) {
#pragma unroll
    for (int s = 0; s < 21; s++) {
      float dist = bd[s];
      int idx = bi[s];
      KNN_INSERT(dist, idx);
    }
    int* nbq = nb + ((size_t)b * N + q) * NB_K;
#pragma unroll
    for (int tt = 0; tt < NB_K; tt++) nbq[tt] = ki[tt + 1];  // drop self (rank 0)
  }
}

// --- small-level knn (1024/256): proven two-pass chunked ladder ---
template <int N, int CHUNK, int NCH>
__global__ void k_knn_part(const float* __restrict__ v, int* __restrict__ part) {
  __shared__ float4 tile[CHUNK];
  int q = blockIdx.x * 64 + threadIdx.x;
  int ch = blockIdx.y;
  int b = blockIdx.z;
  const float* vb = v + (size_t)b * N * 3;
  int cbase = ch * CHUNK;
  for (int j = threadIdx.x; j < CHUNK; j += 64) {
    int g = cbase + j;
    float x = vb[g * 3 + 0], y = vb[g * 3 + 1], z = vb[g * 3 + 2];
    tile[j] = make_float4(x, y, z, fmaf(x, x, fmaf(y, y, z * z)));
  }
  __syncthreads();
  float xq = vb[q * 3 + 0], yq = vb[q * 3 + 1], zq = vb[q * 3 + 2];
  float sqq = fmaf(xq, xq, fmaf(yq, yq, zq * zq));
  float kd[21];
#pragma unroll
  for (int t = 0; t < 21; t++) kd[t] = 3.4e38f;
  for (int j = 0; j < CHUNK; j += 2) {
    float4 c0 = tile[j], c1 = tile[j + 1];
    float d0 = dist_fma(xq, yq, zq, sqq, c0.x, c0.y, c0.z, c0.w);
    float d1 = dist_fma(xq, yq, zq, sqq, c1.x, c1.y, c1.z, c1.w);
    float lo = fminf(d0, d1), hi = fmaxf(d0, d1);
#pragma unroll
    for (int t = 20; t >= 2; --t)
      kd[t] = fminf(fminf(kd[t], fmaxf(kd[t - 1], lo)), fmaxf(kd[t - 2], hi));
    kd[1] = fminf(fminf(kd[1], fmaxf(kd[0], lo)), hi);
    kd[0] = fminf(kd[0], lo);
  }
  float T = kd[20];
  int cnt = 0;
  int* pb = part + (((size_t)b * NCH + ch) * 21) * N + q;
  for (int j = 0; j < CHUNK; ++j) {
    float4 c = tile[j];
    float d = dist_fma(xq, yq, zq, sqq, c.x, c.y, c.z, c.w);
    if (d <= T && cnt < 21) { pb[(size_t)cnt * N] = cbase + j; cnt++; }
  }
}

template <int N, int NCH>
__global__ void k_knn_merge(const float* __restrict__ v, const int* __restrict__ part,
                            int* __restrict__ nb) {
  __shared__ float sx[N], sy[N], sz[N];   // N<=1024 -> <=12 KB
  int q = blockIdx.x * 64 + threadIdx.x;
  int b = blockIdx.y;
  const float* vb = v + (size_t)b * N * 3;
  for (int j = threadIdx.x; j < N; j += 64) {
    sx[j] = vb[j * 3 + 0];
    sy[j] = vb[j * 3 + 1];
    sz[j] = vb[j * 3 + 2];
  }
  __syncthreads();
  float xq = sx[q], yq = sy[q], zq = sz[q];
  float sqq = fmaf(xq, xq, fmaf(yq, yq, zq * zq));
  float kd[21]; int ki[21];
#pragma unroll
  for (int t = 0; t < 21; t++) { kd[t] = 3.4e38f; ki[t] = 0; }
#pragma unroll 1
  for (int ch = 0; ch < NCH; ch++) {
    // preload the whole chunk's 21 indices (independent loads, one latency)
    int idxs[21];
#pragma unroll
    for (int s = 0; s < 21; s++)
      idxs[s] = part[(((size_t)b * NCH + ch) * 21 + s) * N + q];
    // independent dist computations (LDS reads pipeline)
    float dsv[21];
#pragma unroll
    for (int s = 0; s < 21; s++) {
      int j_ = idxs[s];
      float cx = sx[j_], cy = sy[j_], cz = sz[j_];
      float cw = fmaf(cx, cx, fmaf(cy, cy, cz * cz));
      dsv[s] = dist_fma(xq, yq, zq, sqq, cx, cy, cz, cw);
    }
    // chunk fast path: skip whole insertion pass if none qualify
    float mn = dsv[0];
#pragma unroll
    for (int s = 1; s < 21; s++) mn = fminf(mn, dsv[s]);
    if (mn < kd[20]) {
#pragma unroll
      for (int s = 0; s < 21; s++) {
        float dist = dsv[s];
        int idx = idxs[s];
        KNN_INSERT(dist, idx);
      }
    }
  }
  int* nbq = nb + ((size_t)b * N + q) * NB_K;
#pragma unroll
  for (int t = 0; t < NB_K; t++) nbq[t] = ki[t + 1];
}

// ---------------------------------------------------------------------------
// conv_surface
// ---------------------------------------------------------------------------
__global__ void k_surface(const float* __restrict__ v, const int* __restrict__ nb,
                          const float* __restrict__ dirn, float* __restrict__ out) {
  int idx = blockIdx.x * 64 + threadIdx.x;  // b*4096+n
  int b = idx >> 12, n = idx & 4095;
  const float* vb = v + (size_t)b * 4096 * 3;
  float xq = vb[n * 3 + 0], yq = vb[n * 3 + 1], zq = vb[n * 3 + 2];
  float mx[32];
#pragma unroll
  for (int f = 0; f < 32; f++) mx[f] = 0.0f;
  for (int k = 0; k < NB_K; k++) {
    int j = nb[(size_t)idx * NB_K + k];
    float dx = vb[j * 3 + 0] - xq, dy = vb[j * 3 + 1] - yq, dz = vb[j * 3 + 2] - zq;
    float nr = sqrtf((dx * dx + dy * dy) + dz * dz);
    float inv = 1.0f / fmaxf(nr, 1e-12f);
    dx *= inv; dy *= inv; dz *= inv;
#pragma unroll
    for (int f = 0; f < 32; f++) {
      float th = dx * dirn[f] + dy * dirn[32 + f] + dz * dirn[64 + f];
      th = fmaxf(th, 0.0f);
      mx[f] = fmaxf(mx[f], th);
    }
  }
#pragma unroll
  for (int f = 0; f < 32; f++) out[(size_t)idx * 32 + f] = mx[f];
}

// ---------------------------------------------------------------------------
// Tiled fp32 GEMM, BM=128 BN=64 BK=16, 256 thr, 8x4 per thread.
// Requires M%128==0, N%64==0, K%16==0. Accumulation: acc=bias then k
// ascending -- per-output-element fma chain identical to the 64x64 tile and
// to the reference matmul order (bitwise-stable across tile shapes).
// ---------------------------------------------------------------------------
__global__ void k_gemm_tile128(const float* __restrict__ A, const float* __restrict__ W,
                               const float* __restrict__ bias, float* __restrict__ out,
                               int M, int K, int N) {
  __shared__ float As[16][132];   // [k][m] row stride 528 B (16B-aligned reads)
  __shared__ float Bs[16][68];    // [k][n]
  int m0 = blockIdx.y * 128, n0 = blockIdx.x * 64;
  int t = threadIdx.x;
  int tr = t >> 4, tc = t & 15;       // compute: rows tr*8..+7, cols tc*4..+3
  int ar = t >> 2, ak4 = t & 3;       // A load: rows ar and ar+64, k-quad ak4
  int bk = t >> 4, bn4 = t & 15;      // B load: k-row bk, n-quad bn4
  float acc[8][4];
#pragma unroll
  for (int j = 0; j < 4; j++) {
    float bv = bias ? bias[n0 + tc * 4 + j] : 0.0f;
#pragma unroll
    for (int i = 0; i < 8; i++) acc[i][j] = bv;
  }
  for (int k0 = 0; k0 < K; k0 += 16) {
    float4 av0 = *(const float4*)(A + (size_t)(m0 + ar) * K + k0 + ak4 * 4);
    float4 av1 = *(const float4*)(A + (size_t)(m0 + ar + 64) * K + k0 + ak4 * 4);
    float4 wv  = *(const float4*)(W + (size_t)(k0 + bk) * N + n0 + bn4 * 4);
    __syncthreads();
    As[ak4 * 4 + 0][ar] = av0.x;
    As[ak4 * 4 + 1][ar] = av0.y;
    As[ak4 * 4 + 2][ar] = av0.z;
    As[ak4 * 4 + 3][ar] = av0.w;
    As[ak4 * 4 + 0][ar + 64] = av1.x;
    As[ak4 * 4 + 1][ar + 64] = av1.y;
    As[ak4 * 4 + 2][ar + 64] = av1.z;
    As[ak4 * 4 + 3][ar + 64] = av1.w;
    *(float4*)(&Bs[bk][bn4 * 4]) = wv;
    __syncthreads();
#pragma unroll
    for (int kk = 0; kk < 16; kk++) {
      float a[8], b[4];
#pragma unroll
      for (int i = 0; i < 8; i++) a[i] = As[kk][tr * 8 + i];
#pragma unroll
      for (int j = 0; j < 4; j++) b[j] = Bs[kk][tc * 4 + j];
#pragma unroll
      for (int i = 0; i < 8; i++)
#pragma unroll
        for (int j = 0; j < 4; j++) acc[i][j] = fmaf(a[i], b[j], acc[i][j]);
    }
  }
#pragma unroll
  for (int i = 0; i < 8; i++)
    *(float4*)(out + (size_t)(m0 + tr * 8 + i) * N + n0 + tc * 4) =
        make_float4(acc[i][0], acc[i][1], acc[i][2], acc[i][3]);
}

// 64x64 tile kept for the N=64 cluster GEMM (keeps 2x the blocks in flight).
__global__ void k_gemm_tile(const float* __restrict__ A, const float* __restrict__ W,
                            const float* __restrict__ bias, float* __restrict__ out,
                            int M, int K, int N) {
  __shared__ float As[16][68];
  __shared__ float Bs[16][68];
  int m0 = blockIdx.y * 64, n0 = blockIdx.x * 64;
  int t = threadIdx.x;
  int tr = t >> 4, tc = t & 15;
  int am = t >> 2, ak4 = t & 3;       // A load: row am, k-quad ak4
  int bk = t >> 4, bn4 = t & 15;      // B load: k-row bk, n-quad bn4
  float acc[4][4];
#pragma unroll
  for (int j = 0; j < 4; j++) {
    float bv = bias ? bias[n0 + tc * 4 + j] : 0.0f;
#pragma unroll
    for (int i = 0; i < 4; i++) acc[i][j] = bv;
  }
  for (int k0 = 0; k0 < K; k0 += 16) {
    float4 av = *(const float4*)(A + (size_t)(m0 + am) * K + k0 + ak4 * 4);
    float4 wv = *(const float4*)(W + (size_t)(k0 + bk) * N + n0 + bn4 * 4);
    __syncthreads();
    As[ak4 * 4 + 0][am] = av.x;
    As[ak4 * 4 + 1][am] = av.y;
    As[ak4 * 4 + 2][am] = av.z;
    As[ak4 * 4 + 3][am] = av.w;
    *(float4*)(&Bs[bk][bn4 * 4]) = wv;
    __syncthreads();
#pragma unroll
    for (int kk = 0; kk < 16; kk++) {
      float a[4], b[4];
#pragma unroll
      for (int i = 0; i < 4; i++) a[i] = As[kk][tr * 4 + i];
#pragma unroll
      for (int j = 0; j < 4; j++) b[j] = Bs[kk][tc * 4 + j];
#pragma unroll
      for (int i = 0; i < 4; i++)
#pragma unroll
        for (int j = 0; j < 4; j++) acc[i][j] = fmaf(a[i], b[j], acc[i][j]);
    }
  }
#pragma unroll
  for (int i = 0; i < 4; i++)
    *(float4*)(out + (size_t)(m0 + tr * 4 + i) * N + n0 + tc * 4) =
        make_float4(acc[i][0], acc[i][1], acc[i][2], acc[i][3]);
}

// small-M GEMM (gating, M=8)
template <int K>
__global__ void k_gemm4(const float* __restrict__ A, const float* __restrict__ W,
                        const float* __restrict__ bias, float* __restrict__ out,
                        int R, int C) {
  int idx = blockIdx.x * 256 + threadIdx.x;
  int c4 = C >> 2;
  if (idx >= R * c4) return;
  int r = idx / c4, c = (idx - r * c4) << 2;
  const float* a = A + (size_t)r * K;
  float4 acc;
  if (bias) acc = *(const float4*)(bias + c);
  else acc = make_float4(0.f, 0.f, 0.f, 0.f);
#pragma unroll 8
  for (int k = 0; k < K; k++) {
    float av = a[k];
    float4 wv = *(const float4*)(W + (size_t)k * C + c);
    acc.x = fmaf(av, wv.x, acc.x);
    acc.y = fmaf(av, wv.y, acc.y);
    acc.z = fmaf(av, wv.z, acc.z);
    acc.w = fmaf(av, wv.w, acc.w);
  }
  *(float4*)(out + (size_t)r * C + c) = acc;
}

// ---------------------------------------------------------------------------
// conv_layer combine
// ---------------------------------------------------------------------------
template <int COUT, int CPT, bool RELU>
__global__ void k_combine(const float* __restrict__ v, const int* __restrict__ nb,
                          const float* __restrict__ fo, const float* __restrict__ dirn,
                          float* __restrict__ out, int N) {
  constexpr int THREADS = COUT / CPT;
  int bn = blockIdx.x;
  int b = bn / N, n = bn - b * N;
  __shared__ float ds[NB_K][3];
  __shared__ int nbs[NB_K];
  const float* vb = v + (size_t)b * N * 3;
  if (threadIdx.x < NB_K) {
    int j = nb[(size_t)bn * NB_K + threadIdx.x];
    nbs[threadIdx.x] = j;
    float xq = vb[n * 3 + 0], yq = vb[n * 3 + 1], zq = vb[n * 3 + 2];
    float dx = vb[j * 3 + 0] - xq, dy = vb[j * 3 + 1] - yq, dz = vb[j * 3 + 2] - zq;
    float nr = sqrtf((dx * dx + dy * dy) + dz * dz);
    float inv = 1.0f / fmaxf(nr, 1e-12f);
    ds[threadIdx.x][0] = dx * inv;
    ds[threadIdx.x][1] = dy * inv;
    ds[threadIdx.x][2] = dz * inv;
  }
  __syncthreads();
#pragma unroll
  for (int cc = 0; cc < CPT; cc++) {
    int c = threadIdx.x + cc * THREADS;
    float w0 = dirn[c], w1 = dirn[COUT + c], w2 = dirn[2 * COUT + c];
    float acc = -3.4e38f;
    for (int k = 0; k < NB_K; k++) {
      float th = ds[k][0] * w0 + ds[k][1] * w1 + ds[k][2] * w2;
      th = fmaxf(th, 0.0f);
      float fs = fo[((size_t)b * N + nbs[k]) * (2 * COUT) + COUT + c];
      acc = fmaxf(acc, th * fs);
    }
    float res = fo[(size_t)bn * (2 * COUT) + c] + acc;
    if (RELU) res = fmaxf(res, 0.0f);
    out[(size_t)bn * COUT + c] = res;
  }
}

// ---------------------------------------------------------------------------
// gather-max pooling over neighbors
// ---------------------------------------------------------------------------
template <int C>
__global__ void k_gathermax(const float* __restrict__ fm, const int* __restrict__ nb,
                            float* __restrict__ out, int N) {
  int bn = blockIdx.x;
  int b = bn / N;
  __shared__ int nbs[NB_K];
  if (threadIdx.x < NB_K) nbs[threadIdx.x] = nb[(size_t)bn * NB_K + threadIdx.x];
  __syncthreads();
  int c = threadIdx.x;
  float acc = -3.4e38f;
  for (int k = 0; k < NB_K; k++)
    acc = fmaxf(acc, fm[((size_t)b * N + nbs[k]) * C + c]);
  out[(size_t)bn * C + c] = acc;
}

// ---------------------------------------------------------------------------
// pool-index gather
// ---------------------------------------------------------------------------
__global__ void k_poolgather(const float* __restrict__ in, const int* __restrict__ pool,
                             float* __restrict__ out, int n_in, int n_out, int C) {
  int idx = blockIdx.x * 256 + threadIdx.x;
  if (idx >= 8 * n_out * C) return;
  int c = idx % C; int t = idx / C; int i = t % n_out; int b = t / n_out;
  out[idx] = in[((size_t)b * n_in + pool[i]) * C + c];
}

// ---------------------------------------------------------------------------
// GeM pooling, n-split 4-way (32 -> 512 waves). Partial sums combined in
// fixed order ((p0+p1)+p2)+p3 -- deterministic, ~1e-7 rel vs serial order.
// ---------------------------------------------------------------------------
__global__ void k_gem(const float* __restrict__ fm4, const float* __restrict__ gp,
                      float* __restrict__ y) {
  __shared__ float red[4][64];
  int blk = blockIdx.x;            // 8*16 = 128 blocks
  int b = blk >> 4, f0 = (blk & 15) << 6;
  int fl = threadIdx.x & 63, ng = threadIdx.x >> 6;
  int f = f0 + fl;
  float p = gp[0];
  float s = 0.0f;
  const float* base = fm4 + (size_t)b * 256 * 1024 + f;
  if (p == 3.0f) {
    for (int n = ng * 64; n < ng * 64 + 64; n++) {
      float val = fmaxf(base[(size_t)n * 1024], 1e-6f);
      s += val * val * val;
    }
  } else {
    for (int n = ng * 64; n < ng * 64 + 64; n++) {
      float val = fmaxf(base[(size_t)n * 1024], 1e-6f);
      s += powf(val, p);
    }
  }
  red[ng][fl] = s;
  __syncthreads();
  if (ng == 0) {
    float st = ((red[0][fl] + red[1][fl]) + red[2][fl]) + red[3][fl];
    y[b * 1024 + f] = powf(st * (1.0f / 256.0f), 1.0f / p);
  }
}

// ---------------------------------------------------------------------------
// NetVLAD pieces
// ---------------------------------------------------------------------------
__global__ void k_bnstats(const float* __restrict__ x, int R, int C,
                          float* __restrict__ mean, float* __restrict__ rstd) {
  int c = blockIdx.x;
  __shared__ float red[256];
  float s = 0.0f;
  for (int r = threadIdx.x; r < R; r += 256) s += x[(size_t)r * C + c];
  red[threadIdx.x] = s; __syncthreads();
  for (int st = 128; st > 0; st >>= 1) {
    if (threadIdx.x < st) red[threadIdx.x] += red[threadIdx.x + st];
    __syncthreads();
  }
  float m = red[0] / (float)R;
  __syncthreads();
  float s2 = 0.0f;
  for (int r = threadIdx.x; r < R; r += 256) {
    float d = x[(size_t)r * C + c] - m; s2 += d * d;
  }
  red[threadIdx.x] = s2; __syncthreads();
  for (int st = 128; st > 0; st >>= 1) {
    if (threadIdx.x < st) red[threadIdx.x] += red[threadIdx.x + st];
    __syncthreads();
  }
  if (threadIdx.x == 0) {
    mean[c] = m;
    rstd[c] = 1.0f / sqrtf(red[0] / (float)R + BN_EPS);
  }
}

__global__ void k_softmax(const float* __restrict__ a0, const float* __restrict__ mean,
                          const float* __restrict__ rstd, const float* __restrict__ g,
                          const float* __restrict__ bb, float* __restrict__ act) {
  int r = blockIdx.x, c = threadIdx.x;
  float x = (a0[(size_t)r * 64 + c] - mean[c]) * rstd[c] * g[c] + bb[c];
  float mx = x;
  for (int off = 32; off > 0; off >>= 1) mx = fmaxf(mx, __shfl_xor(mx, off));
  float e = expf(x - mx);
  float sm = e;
  for (int off = 32; off > 0; off >>= 1) sm += __shfl_xor(sm, off);
  act[(size_t)r * 64 + c] = e / sm;
}

// m-split 4-way (8 -> 32 waves); ordered partial combine.
__global__ void k_colsum(const float* __restrict__ act, float* __restrict__ asum) {
  __shared__ float red[4][64];
  int b = blockIdx.x;
  int k = threadIdx.x & 63, mg = threadIdx.x >> 6;
  float s = 0.0f;
  for (int m = mg * 64; m < mg * 64 + 64; m++) s += act[((size_t)b * 256 + m) * 64 + k];
  red[mg][k] = s;
  __syncthreads();
  if (mg == 0)
    asum[b * 64 + k] = ((red[0][k] + red[1][k]) + red[2][k]) + red[3][k];
}

// vlad[b,f,k] = sum_m xv[b,m,f]*act[b,m,k] - asum[b,k]*cw2[f,k]
// tiled: block (f-tile 64 x k 64), LDS-staged, 4x4 per thread
__global__ void k_vlad_tile(const float* __restrict__ act, const float* __restrict__ xv,
                            const float* __restrict__ asum, const float* __restrict__ cw2,
                            float* __restrict__ vlad) {
  __shared__ float Xs[64][68];   // [m][f]
  __shared__ float Ac[64][68];   // [m][k]
  int b = blockIdx.y, f0 = blockIdx.x * 64;
  int t = threadIdx.x, tr = t >> 4, tc = t & 15;
  float acc[4][4] = {};
  for (int m0 = 0; m0 < 256; m0 += 64) {
    __syncthreads();
#pragma unroll
    for (int r = 0; r < 4; r++) {
      int m = r * 16 + (t >> 4);
      *(float4*)(&Xs[m][(t & 15) * 4]) =
          *(const float4*)(xv + ((size_t)b * 256 + m0 + m) * 1024 + f0 + (t & 15) * 4);
      *(float4*)(&Ac[m][(t & 15) * 4]) =
          *(const float4*)(act + ((size_t)b * 256 + m0 + m) * 64 + (t & 15) * 4);
    }
    __syncthreads();
    for (int mm = 0; mm < 64; mm++) {
      float a[4], c[4];
#pragma unroll
      for (int i = 0; i < 4; i++) a[i] = Xs[mm][tr * 4 + i];
#pragma unroll
      for (int j = 0; j < 4; j++) c[j] = Ac[mm][tc * 4 + j];
#pragma unroll
      for (int i = 0; i < 4; i++)
#pragma unroll
        for (int j = 0; j < 4; j++) acc[i][j] = fmaf(a[i], c[j], acc[i][j]);
    }
  }
#pragma unroll
  for (int i = 0; i < 4; i++) {
    int f = f0 + tr * 4 + i;
#pragma unroll
    for (int j = 0; j < 4; j++) {
      int k = tc * 4 + j;
      vlad[((size_t)b * 1024 + f) * 64 + k] = acc[i][j] - asum[b * 64 + k] * cw2[f * 64 + k];
    }
  }
}

__global__ void k_norm1(const float* __restrict__ vlad, float* __restrict__ scale1) {
  int bk = blockIdx.x;  // b*64+k
  int b = bk >> 6, k = bk & 63;
  float s = 0.0f;
  for (int f = threadIdx.x; f < 1024; f += 64) {
    float val = vlad[((size_t)b * 1024 + f) * 64 + k];
    s += val * val;
  }
  for (int off = 32; off > 0; off >>= 1) s += __shfl_xor(s, off);
  if (threadIdx.x == 0) scale1[bk] = 1.0f / fmaxf(sqrtf(s), 1e-12f);
}

__global__ void k_norm2(const float* __restrict__ vlad, const float* __restrict__ scale1,
                        float* __restrict__ scale2) {
  int b = blockIdx.x;
  __shared__ float red[256];
  float s = 0.0f;
  for (int i = threadIdx.x; i < 65536; i += 256) {
    float val = vlad[(size_t)b * 65536 + i] * scale1[b * 64 + (i & 63)];
    s += val * val;
  }
  red[threadIdx.x] = s; __syncthreads();
  for (int st = 128; st > 0; st >>= 1) {
    if (threadIdx.x < st) red[threadIdx.x] += red[threadIdx.x + st];
    __syncthreads();
  }
  if (threadIdx.x == 0) scale2[b] = 1.0f / fmaxf(sqrtf(red[0]), 1e-12f);
}

__global__ void k_vscale(float* __restrict__ vlad, const float* __restrict__ scale1,
                         const float* __restrict__ scale2) {
  int idx = blockIdx.x * 256 + threadIdx.x;
  int b = idx >> 16; int r = idx & 65535;
  vlad[idx] = vlad[idx] * scale1[b * 64 + (r & 63)] * scale2[b];
}

__global__ void k_hidden_partial(const float* __restrict__ vlad, const float* __restrict__ hw,
                                 float* __restrict__ partial) {
  __shared__ float vs[8][512];
  int cg = blockIdx.x;   // 0..3
  int kb = blockIdx.y;   // 0..127
  int col = cg * 256 + threadIdx.x;
  int k0 = kb * 512;
  for (int i = threadIdx.x; i < 8 * 512; i += 256) {
    int b = i >> 9, k = i & 511;
    vs[b][k] = vlad[(size_t)b * 65536 + k0 + k];
  }
  __syncthreads();
  float acc[8] = {0, 0, 0, 0, 0, 0, 0, 0};
  for (int k = 0; k < 512; k++) {
    float w = hw[(size_t)(k0 + k) * 1024 + col];
#pragma unroll
    for (int b = 0; b < 8; b++) acc[b] += vs[b][k] * w;
  }
#pragma unroll
  for (int b = 0; b < 8; b++)
    partial[((size_t)kb * 8 + b) * 1024 + col] = acc[b];
}

__global__ void k_hidden_reduce(const float* __restrict__ partial, float* __restrict__ hid) {
  int idx = blockIdx.x * 256 + threadIdx.x;  // b*1024+c
  int b = idx >> 10, c = idx & 1023;
  float s = 0.0f;
  for (int kb = 0; kb < 128; kb++) s += partial[((size_t)kb * 8 + b) * 1024 + c];
  hid[idx] = s;
}

__global__ void k_bn8(const float* __restrict__ x, const float* __restrict__ g,
                      const float* __restrict__ bb, float* __restrict__ out) {
  int c = blockIdx.x * 256 + threadIdx.x;
  if (c >= 1024) return;
  float v[8]; float s = 0.0f;
#pragma unroll
  for (int b = 0; b < 8; b++) { v[b] = x[b * 1024 + c]; s += v[b]; }
  float m = s * 0.125f; float s2 = 0.0f;
#pragma unroll
  for (int b = 0; b < 8; b++) { float d = v[b] - m; s2 += d * d; }
  float rstd = 1.0f / sqrtf(s2 * 0.125f + BN_EPS);
#pragma unroll
  for (int b = 0; b < 8; b++) out[b * 1024 + c] = (v[b] - m) * rstd * g[c] + bb[c];
}

__global__ void k_gbn_out(const float* __restrict__ gat, const float* __restrict__ g,
                          const float* __restrict__ bb, const float* __restrict__ vladbn,
                          float* __restrict__ desc) {
  int c = blockIdx.x * 256 + threadIdx.x;
  if (c >= 1024) return;
  float v[8]; float s = 0.0f;
#pragma unroll
  for (int b = 0; b < 8; b++) { v[b] = gat[b * 1024 + c]; s += v[b]; }
  float m = s * 0.125f; float s2 = 0.0f;
#pragma unroll
  for (int b = 0; b < 8; b++) { float d = v[b] - m; s2 += d * d; }
  float rstd = 1.0f / sqrtf(s2 * 0.125f + BN_EPS);
#pragma unroll
  for (int b = 0; b < 8; b++) {
    float x = (v[b] - m) * rstd * g[c] + bb[c];
    float gate = 1.0f / (1.0f + expf(-x));
    desc[b * 1024 + c] = vladbn[b * 1024 + c] * gate;
  }
}

// ---------------------------------------------------------------------------
// launch
// ---------------------------------------------------------------------------
extern "C" void kernel_launch(void* const* d_in, const int* in_sizes, int n_in,
                              void* d_out, int out_size, void* d_ws, size_t ws_size,
                              hipStream_t stream) {
  (void)in_sizes; (void)n_in; (void)out_size; (void)ws_size;
  const float* x    = (const float*)d_in[0];
  const float* dir0 = (const float*)d_in[1];
  const float* W1   = (const float*)d_in[2];
  const float* b1   = (const float*)d_in[3];
  const float* dir1 = (const float*)d_in[4];
  const float* W2   = (const float*)d_in[5];
  const float* b2   = (const float*)d_in[6];
  const float* dir2 = (const float*)d_in[7];
  const float* W3   = (const float*)d_in[8];
  const float* b3   = (const float*)d_in[9];
  const float* dir3 = (const float*)d_in[10];
  const float* W4   = (const float*)d_in[11];
  const float* b4   = (const float*)d_in[12];
  const float* dir4 = (const float*)d_in[13];
  const float* gemp = (const float*)d_in[14];
  const float* cw   = (const float*)d_in[15];
  const float* cw2  = (const float*)d_in[16];
  const float* hw   = (const float*)d_in[17];
  const float* bn1g = (const float*)d_in[18];
  const float* bn1b = (const float*)d_in[19];
  const float* bn2g = (const float*)d_in[20];
  const float* bn2b = (const float*)d_in[21];
  const float* gw   = (const float*)d_in[22];
  const float* gbng = (const float*)d_in[23];
  const float* gbnb = (const float*)d_in[24];
  float* out = (float*)d_out;
  char* ws = (char*)d_ws;

  float* F_DIRN0 = (float*)(ws + OFF_DIRN0);
  float* F_DIRN1 = (float*)(ws + OFF_DIRN1);
  float* F_DIRN2 = (float*)(ws + OFF_DIRN2);
  float* F_DIRN3 = (float*)(ws + OFF_DIRN3);
  float* F_DIRN4 = (float*)(ws + OFF_DIRN4);
  int*   I_POOL1 = (int*)(ws + OFF_POOL1);
  int*   I_POOL2 = (int*)(ws + OFF_POOL2);
  int*   I_NB    = (int*)(ws + OFF_NB);
  int*   I_KPART = (int*)(ws + OFF_KPART);
  unsigned short* U_KSURV = (unsigned short*)(ws + OFF_KSURV);
  int*   I_KCNT  = (int*)(ws + OFF_KCNT);
  float* F_KT0   = (float*)(ws + OFF_KT0);
  float* F_V2    = (float*)(ws + OFF_V2);
  float* F_V3    = (float*)(ws + OFF_V3);
  float* F_X1    = (float*)(ws + OFF_X1);
  float* F_X2    = (float*)(ws + OFF_X2);
  float* F_X3    = (float*)(ws + OFF_X3);
  float* F_X4    = (float*)(ws + OFF_X4);

  hipMemcpyAsync(I_POOL1, g_pools.p1, sizeof(g_pools.p1), hipMemcpyHostToDevice, stream);
  hipMemcpyAsync(I_POOL2, g_pools.p2, sizeof(g_pools.p2), hipMemcpyHostToDevice, stream);

  k_dirnorm<<<6, 256, 0, stream>>>(dir0, dir1, dir2, dir3, dir4,
                                   F_DIRN0, F_DIRN1, F_DIRN2, F_DIRN3, F_DIRN4);

  // ---- level 0: 4096 pts (sample -> filter -> merge) ----
  k_knn_sample<4096, 512><<<dim3(64, 8), 64, 0, stream>>>(x, F_KT0);
  k_knn_filter<4096, 512, 8, 64><<<dim3(64, 8, 8), 64, 0, stream>>>(x, F_KT0, U_KSURV, I_KCNT);
  k_knn_merge2<4096, 8, 64><<<dim3(128, 8), 64, 0, stream>>>(x, U_KSURV, I_KCNT, I_NB);
  k_surface<<<512, 64, 0, stream>>>(x, I_NB, F_DIRN0, F_X3);
  k_gemm_tile128<<<dim3(2, 256), 256, 0, stream>>>(F_X3, W1, b1, F_X1, 32768, 32, 128);
  k_combine<64, 1, true><<<32768, 64, 0, stream>>>(x, I_NB, F_X1, F_DIRN1, F_X4, 4096);
  k_gathermax<64><<<32768, 64, 0, stream>>>(F_X4, I_NB, F_X2, 4096);
  k_poolgather<<<(8 * 1024 * 3 + 255) / 256, 256, 0, stream>>>(x, I_POOL1, F_V2, 4096, 1024, 3);
  k_poolgather<<<(8 * 1024 * 64 + 255) / 256, 256, 0, stream>>>(F_X2, I_POOL1, F_X3, 4096, 1024, 64);

  // ---- level 1: 1024 pts ----
  k_knn_part<1024, 128, 8><<<dim3(16, 8, 8), 64, 0, stream>>>(F_V2, I_KPART);
  k_knn_merge<1024, 8><<<dim3(16, 8), 64, 0, stream>>>(F_V2, I_KPART, I_NB);
  k_gemm_tile128<<<dim3(4, 64), 256, 0, stream>>>(F_X3, W2, b2, F_X4, 8192, 64, 256);
  k_combine<128, 1, true><<<8192, 128, 0, stream>>>(F_V2, I_NB, F_X4, F_DIRN2, F_X1, 1024);
  k_gemm_tile128<<<dim3(8, 64), 256, 0, stream>>>(F_X1, W3, b3, F_X2, 8192, 128, 512);
  k_combine<256, 1, true><<<8192, 256, 0, stream>>>(F_V2, I_NB, F_X2, F_DIRN3, F_X4, 1024);
  k_gathermax<256><<<8192, 256, 0, stream>>>(F_X4, I_NB, F_X1, 1024);
  k_poolgather<<<(8 * 256 * 3 + 255) / 256, 256, 0, stream>>>(F_V2, I_POOL2, F_V3, 1024, 256, 3);
  k_poolgather<<<(8 * 256 * 256 + 255) / 256, 256, 0, stream>>>(F_X1, I_POOL2, F_X3, 1024, 256, 256);

  // ---- level 2: 256 pts ----
  k_knn_part<256, 64, 4><<<dim3(4, 4, 8), 64, 0, stream>>>(F_V3, I_KPART);
  k_knn_merge<256, 4><<<dim3(4, 8), 64, 0, stream>>>(F_V3, I_KPART, I_NB);
  k_gemm_tile128<<<dim3(32, 16), 256, 0, stream>>>(F_X3, W4, b4, F_X2, 2048, 256, 2048);
  k_combine<1024, 4, false><<<2048, 256, 0, stream>>>(F_V3, I_NB, F_X2, F_DIRN4, F_X4, 256);

  // ---- GeM head -> out[0:8192] ----
  k_gem<<<128, 256, 0, stream>>>(F_X4, gemp, out);

  // ---- NetVLAD head -> out[8192:16384] ----
  float* F_ACT0 = (float*)(ws + OFF_ACT0);
  float* F_ACT  = (float*)(ws + OFF_ACT);
  float* F_VLAD = (float*)(ws + OFF_VLAD);
  float* F_PART = (float*)(ws + OFF_PART);
  float* F_BN1M = (float*)(ws + OFF_BN1M);
  float* F_BN1R = (float*)(ws + OFF_BN1R);
  float* F_ASUM = (float*)(ws + OFF_ASUM);
  float* F_SC1  = (float*)(ws + OFF_SCALE1);
  float* F_SC2  = (float*)(ws + OFF_SCALE2);
  float* F_HID  = (float*)(ws + OFF_HID);
  float* F_VBN  = (float*)(ws + OFF_VLADBN);
  float* F_GAT  = (float*)(ws + OFF_GAT);

  k_gemm_tile<<<dim3(1, 32), 256, 0, stream>>>(F_X4, cw, nullptr, F_ACT0, 2048, 1024, 64);
  k_bnstats<<<64, 256, 0, stream>>>(F_ACT0, 2048, 64, F_BN1M, F_BN1R);
  k_softmax<<<2048, 64, 0, stream>>>(F_ACT0, F_BN1M, F_BN1R, bn1g, bn1b, F_ACT);
  k_colsum<<<8, 256, 0, stream>>>(F_ACT, F_ASUM);
  k_vlad_tile<<<dim3(16, 8), 256, 0, stream>>>(F_ACT, F_X4, F_ASUM, cw2, F_VLAD);
  k_norm1<<<512, 64, 0, stream>>>(F_VLAD, F_SC1);
  k_norm2<<<8, 256, 0, stream>>>(F_VLAD, F_SC1, F_SC2);
  k_vscale<<<(8 * 65536) / 256, 256, 0, stream>>>(F_VLAD, F_SC1, F_SC2);
  k_hidden_partial<<<dim3(4, 128), 256, 0, stream>>>(F_VLAD, hw, F_PART);
  k_hidden_reduce<<<32, 256, 0, stream>>>(F_PART, F_HID);
  k_bn8<<<4, 256, 0, stream>>>(F_HID, bn2g, bn2b, F_VBN);
  k_gemm4<1024><<<(8 * 256 + 255) / 256, 256, 0, stream>>>(F_VBN, gw, nullptr, F_GAT, 8, 1024);
  k_gbn_out<<<4, 256, 0, stream>>>(F_GAT, gbng, gbnb, F_VBN, out + 8192);
}

// Round 5
// 1304.903 us; speedup vs baseline: 1.0494x; 1.0494x over previous
//
#include <hip/hip_runtime.h>
#include <math.h>

// ============================================================================
// SBDD point-cloud network, fp32, bs=8, N_PTS=4096, NB=20, S=1.
// R1: LDS-stage coordinates in kNN merge kernels.
// R2: break survivor-index load serialization (filter pads to x4 sentinels,
//     merge2 4-deep index prefetch, small merges preload 21 idx).
// R3: 128x64 fp32 GEMM tile; kNN insert group-skip; 8-deep prefetch.
// R4: k_gem / k_colsum reduction split 4-way (ordered partial combine).
//     [merge2 2-thread/query REVERTED in R5: doubled LDS staging traffic +
//      pair-divergence cost +76 us; single-thread/query R3 form restored.]
// ============================================================================

#define NB_K 20
#define BN_EPS 1e-5f

// ---------------------------------------------------------------------------
// Host-side reproduction of np.random.RandomState(seed).permutation(n)
// ---------------------------------------------------------------------------
namespace {
struct MT19937H {
  unsigned mt[624]; int pos;
  void seed(unsigned s) {
    for (int i = 0; i < 624; i++) { mt[i] = s; s = 1812433253u * (s ^ (s >> 30)) + (unsigned)i + 1u; }
    pos = 624;
  }
  unsigned next() {
    if (pos >= 624) {
      for (int i = 0; i < 624; i++) {
        unsigned y = (mt[i] & 0x80000000u) | (mt[(i + 1) % 624] & 0x7fffffffu);
        unsigned v = mt[(i + 397) % 624] ^ (y >> 1);
        if (y & 1u) v ^= 0x9908b0dfu;
        mt[i] = v;
      }
      pos = 0;
    }
    unsigned y = mt[pos++];
    y ^= y >> 11; y ^= (y << 7) & 0x9d2c5680u; y ^= (y << 15) & 0xefc60000u; y ^= y >> 18;
    return y;
  }
  unsigned interval(unsigned mx) {
    if (mx == 0) return 0;
    unsigned mask = mx;
    mask |= mask >> 1; mask |= mask >> 2; mask |= mask >> 4; mask |= mask >> 8; mask |= mask >> 16;
    unsigned v;
    do { v = next() & mask; } while (v > mx);
    return v;
  }
};
struct Pools {
  int p1[1024];
  int p2[256];
  int arr[4096];
  Pools() {
    MT19937H m;
    m.seed(1);
    for (int i = 0; i < 4096; i++) arr[i] = i;
    for (int i = 4095; i >= 1; i--) {
      int j = (int)m.interval((unsigned)i);
      int t = arr[j]; arr[j] = arr[i]; arr[i] = t;
    }
    for (int i = 0; i < 1024; i++) p1[i] = arr[i];
    m.seed(2);
    for (int i = 0; i < 1024; i++) arr[i] = i;
    for (int i = 1023; i >= 1; i--) {
      int j = (int)m.interval((unsigned)i);
      int t = arr[j]; arr[j] = arr[i]; arr[i] = t;
    }
    for (int i = 0; i < 256; i++) p2[i] = arr[i];
  }
};
Pools g_pools;
}

// ---------------------------------------------------------------------------
// Workspace layout (bytes).
// ---------------------------------------------------------------------------
#define OFF_POOL1   (0u)
#define OFF_POOL2   (16u << 10)
#define OFF_DIRN0   (32u << 10)
#define OFF_DIRN1   (36u << 10)
#define OFF_DIRN2   (40u << 10)
#define OFF_DIRN3   (48u << 10)
#define OFF_DIRN4   (56u << 10)
#define OFF_V2      (128u << 10)
#define OFF_V3      (256u << 10)
#define OFF_BN1M    (288u << 10)
#define OFF_BN1R    (292u << 10)
#define OFF_ASUM    (296u << 10)
#define OFF_SCALE1  (304u << 10)
#define OFF_SCALE2  (312u << 10)
#define OFF_HID     (320u << 10)
#define OFF_VLADBN  (352u << 10)
#define OFF_GAT     (384u << 10)
#define OFF_NB      (1u << 20)          // neighbor idx, reused all stages
#define OFF_X1      (4u << 20)          // 16 MB
#define OFF_X2      (20u << 20)         // 16 MB
#define OFF_X3      (36u << 20)         // 8 MB
#define OFF_X4      (44u << 20)         // 8 MB
// knn4096 scratch (X regions free during knn): surv 32MB @X1, cnt 1MB @X3, T0 @X4
#define OFF_KSURV   (OFF_X1)
#define OFF_KCNT    (OFF_X3)
#define OFF_KT0     (OFF_X4)
#define OFF_KPART   (OFF_X1)            // small-level knn partials
#define OFF_ACT0    (OFF_X1)
#define OFF_ACT     (OFF_X1 + (1u << 20))
#define OFF_VLAD    (OFF_X1 + (2u << 20))
#define OFF_PART    (OFF_X1 + (8u << 20))

// ---------------------------------------------------------------------------
// dir normalization: l2norm(dirs, axis=0)
// ---------------------------------------------------------------------------
__global__ void k_dirnorm(const float* __restrict__ d0, const float* __restrict__ d1,
                          const float* __restrict__ d2, const float* __restrict__ d3,
                          const float* __restrict__ d4,
                          float* __restrict__ o0, float* __restrict__ o1,
                          float* __restrict__ o2, float* __restrict__ o3,
                          float* __restrict__ o4) {
  int i = blockIdx.x * 256 + threadIdx.x;
  const float* src; float* dst; int F, c;
  if      (i < 32)   { src = d0; dst = o0; F = 32;   c = i; }
  else if (i < 96)   { src = d1; dst = o1; F = 64;   c = i - 32; }
  else if (i < 224)  { src = d2; dst = o2; F = 128;  c = i - 96; }
  else if (i < 480)  { src = d3; dst = o3; F = 256;  c = i - 224; }
  else if (i < 1504) { src = d4; dst = o4; F = 1024; c = i - 480; }
  else return;
  float a = src[c], b = src[F + c], cc = src[2 * F + c];
  float nr = sqrtf((a * a + b * b) + cc * cc);
  float inv = 1.0f / fmaxf(nr, 1e-12f);
  dst[c] = a * inv; dst[F + c] = b * inv; dst[2 * F + c] = cc * inv;
}

// ---------------------------------------------------------------------------
// kNN. dist via fixed fma chain so all kernels agree bitwise; self-dist == 0.
// ---------------------------------------------------------------------------
__device__ __forceinline__ float dist_fma(float xq, float yq, float zq, float sqq,
                                          float cx, float cy, float cz, float cw) {
  float dot = fmaf(xq, cx, fmaf(yq, cy, zq * cz));
  return fmaf(-2.0f, dot, sqq + cw);
}

// insertion into sorted 21-deep (dist,idx) list; strict < keeps stable
// lowest-index-first tie order identical to jax.lax.top_k.
#define KNN_INSERT(DIST, IDX)                                                 \
  if ((DIST) < kd[20]) {                                                      \
    _Pragma("unroll")                                                         \
    for (int t_ = 20; t_ >= 1; t_--) {                                        \
      bool shift_ = (DIST) < kd[t_ - 1];                                      \
      float nk_ = shift_ ? kd[t_ - 1] : (DIST);                               \
      int   ni_ = shift_ ? ki[t_ - 1] : (IDX);                                \
      bool upd_ = (DIST) < kd[t_];                                            \
      if (upd_) { kd[t_] = nk_; ki[t_] = ni_; }                               \
    }                                                                         \
    if ((DIST) < kd[0]) { kd[0] = (DIST); ki[0] = (IDX); }                    \
  }

// --- knn4096 scheme: sample (exact 21st of first 512) -> filter -> merge ---
template <int N, int SAMPLE>
__global__ void k_knn_sample(const float* __restrict__ v, float* __restrict__ T0) {
  __shared__ float4 tile[SAMPLE];
  int q = blockIdx.x * 64 + threadIdx.x;
  int b = blockIdx.y;
  const float* vb = v + (size_t)b * N * 3;
  for (int j = threadIdx.x; j < SAMPLE; j += 64) {
    float x = vb[j * 3 + 0], y = vb[j * 3 + 1], z = vb[j * 3 + 2];
    tile[j] = make_float4(x, y, z, fmaf(x, x, fmaf(y, y, z * z)));
  }
  __syncthreads();
  float xq = vb[q * 3 + 0], yq = vb[q * 3 + 1], zq = vb[q * 3 + 2];
  float sqq = fmaf(xq, xq, fmaf(yq, yq, zq * zq));
  float kd[21];
#pragma unroll
  for (int t = 0; t < 21; t++) kd[t] = 3.4e38f;
  for (int j = 0; j < SAMPLE; j += 2) {
    float4 c0 = tile[j], c1 = tile[j + 1];
    float d0 = dist_fma(xq, yq, zq, sqq, c0.x, c0.y, c0.z, c0.w);
    float d1 = dist_fma(xq, yq, zq, sqq, c1.x, c1.y, c1.z, c1.w);
    float lo = fminf(d0, d1), hi = fmaxf(d0, d1);
#pragma unroll
    for (int t = 20; t >= 2; --t)
      kd[t] = fminf(fminf(kd[t], fmaxf(kd[t - 1], lo)), fmaxf(kd[t - 2], hi));
    kd[1] = fminf(fminf(kd[1], fmaxf(kd[0], lo)), hi);
    kd[0] = fminf(kd[0], lo);
  }
  T0[(size_t)b * N + q] = kd[20];  // >= global 21st-smallest (sample superset bound)
}

template <int N, int CHUNK, int NCH, int SLOTS>
__global__ void k_knn_filter(const float* __restrict__ v, const float* __restrict__ T0,
                             unsigned short* __restrict__ surv, int* __restrict__ cnt) {
  __shared__ float4 tile[CHUNK];
  int q = blockIdx.x * 64 + threadIdx.x;
  int ch = blockIdx.y;
  int b = blockIdx.z;
  const float* vb = v + (size_t)b * N * 3;
  int cbase = ch * CHUNK;
  for (int j = threadIdx.x; j < CHUNK; j += 64) {
    int g = cbase + j;
    float x = vb[g * 3 + 0], y = vb[g * 3 + 1], z = vb[g * 3 + 2];
    tile[j] = make_float4(x, y, z, fmaf(x, x, fmaf(y, y, z * z)));
  }
  __syncthreads();
  float xq = vb[q * 3 + 0], yq = vb[q * 3 + 1], zq = vb[q * 3 + 2];
  float sqq = fmaf(xq, xq, fmaf(yq, yq, zq * zq));
  float T = T0[(size_t)b * N + q];
  int c = 0;
  unsigned short* sb = surv + ((size_t)b * NCH + ch) * SLOTS * N + q;
  for (int j = 0; j < CHUNK; ++j) {
    float4 cd = tile[j];
    float d = dist_fma(xq, yq, zq, sqq, cd.x, cd.y, cd.z, cd.w);
    if (d <= T && c < SLOTS) {
      sb[(size_t)c * N] = (unsigned short)(cbase + j);
      c++;
    }
  }
  // pad to multiple of 4 with sentinels so merge can run uniform 4-groups
  while (c & 3) { sb[(size_t)c * N] = 0xFFFFu; c++; }
  cnt[((size_t)b * NCH + ch) * N + q] = c;
}

// merge with LDS-staged coordinates + 8-deep (two-group) prefetch and a
// min-of-group fast path that skips the whole 21-stage insertion network
// when no candidate in the group can qualify (exact: strict < comparison).
// 1 thread/query (R3 form; the 2-thread/query split doubled LDS staging
// traffic and paid pair-divergence -- measured +76 us, reverted).
template <int N, int NCH, int SLOTS>
__global__ void k_knn_merge2(const float* __restrict__ v, const unsigned short* __restrict__ surv,
                             const int* __restrict__ cnt, int* __restrict__ nb) {
  __shared__ float sx[N], sy[N], sz[N];   // N=4096 -> 48 KB
  int q = blockIdx.x * 64 + threadIdx.x;
  int b = blockIdx.y;
  const float* vb = v + (size_t)b * N * 3;
  for (int j = threadIdx.x; j < N; j += 64) {
    sx[j] = vb[j * 3 + 0];
    sy[j] = vb[j * 3 + 1];
    sz[j] = vb[j * 3 + 2];
  }
  __syncthreads();
  float xq = sx[q], yq = sy[q], zq = sz[q];
  float sqq = fmaf(xq, xq, fmaf(yq, yq, zq * zq));
  // hoist all chunk counts (8 independent loads, one latency)
  int cns[NCH];
#pragma unroll
  for (int ch = 0; ch < NCH; ch++) cns[ch] = cnt[((size_t)b * NCH + ch) * N + q];
  float kd[21]; int ki[21];
#pragma unroll
  for (int t = 0; t < 21; t++) { kd[t] = 3.4e38f; ki[t] = 0; }
#pragma unroll 1
  for (int ch = 0; ch < NCH; ch++) {
    int cn = cns[ch];                    // multiple of 4 (filter pads)
    const unsigned short* sb = surv + ((size_t)b * NCH + ch) * SLOTS * N + q;
    int ia0 = 0xFFFF, ia1 = 0xFFFF, ia2 = 0xFFFF, ia3 = 0xFFFF;
    int ib0 = 0xFFFF, ib1 = 0xFFFF, ib2 = 0xFFFF, ib3 = 0xFFFF;
    if (cn > 0) {
      ia0 = sb[0];
      ia1 = sb[(size_t)1 * N];
      ia2 = sb[(size_t)2 * N];
      ia3 = sb[(size_t)3 * N];
    }
    if (cn > 4) {
      ib0 = sb[(size_t)4 * N];
      ib1 = sb[(size_t)5 * N];
      ib2 = sb[(size_t)6 * N];
      ib3 = sb[(size_t)7 * N];
    }
#pragma unroll 1
    for (int s = 0; s < cn; s += 4) {
      int n0 = 0xFFFF, n1 = 0xFFFF, n2 = 0xFFFF, n3 = 0xFFFF;
      if (s + 8 < cn) {
        n0 = sb[(size_t)(s + 8) * N];
        n1 = sb[(size_t)(s + 9) * N];
        n2 = sb[(size_t)(s + 10) * N];
        n3 = sb[(size_t)(s + 11) * N];
      }
      // 4 independent dist computations (LDS reads pipeline)
      float d0, d1, d2, d3;
      {
        int j_ = ia0 & (N - 1);
        float cx = sx[j_], cy = sy[j_], cz = sz[j_];
        float cw = fmaf(cx, cx, fmaf(cy, cy, cz * cz));
        d0 = (ia0 >= N) ? 3.4e38f : dist_fma(xq, yq, zq, sqq, cx, cy, cz, cw);
      }
      {
        int j_ = ia1 & (N - 1);
        float cx = sx[j_], cy = sy[j_], cz = sz[j_];
        float cw = fmaf(cx, cx, fmaf(cy, cy, cz * cz));
        d1 = (ia1 >= N) ? 3.4e38f : dist_fma(xq, yq, zq, sqq, cx, cy, cz, cw);
      }
      {
        int j_ = ia2 & (N - 1);
        float cx = sx[j_], cy = sy[j_], cz = sz[j_];
        float cw = fmaf(cx, cx, fmaf(cy, cy, cz * cz));
        d2 = (ia2 >= N) ? 3.4e38f : dist_fma(xq, yq, zq, sqq, cx, cy, cz, cw);
      }
      {
        int j_ = ia3 & (N - 1);
        float cx = sx[j_], cy = sy[j_], cz = sz[j_];
        float cw = fmaf(cx, cx, fmaf(cy, cy, cz * cz));
        d3 = (ia3 >= N) ? 3.4e38f : dist_fma(xq, yq, zq, sqq, cx, cy, cz, cw);
      }
      // group fast path: skip the whole insertion network if none qualify
      float mind = fminf(fminf(d0, d1), fminf(d2, d3));
      if (mind < kd[20]) {
        KNN_INSERT(d0, ia0);
        KNN_INSERT(d1, ia1);
        KNN_INSERT(d2, ia2);
        KNN_INSERT(d3, ia3);
      }
      ia0 = ib0; ia1 = ib1; ia2 = ib2; ia3 = ib3;
      ib0 = n0;  ib1 = n1;  ib2 = n2;  ib3 = n3;
    }
  }
  int* nbq = nb + ((size_t)b * N + q) * NB_K;
#pragma unroll
  for (int t = 0; t < NB_K; t++) nbq[t] = ki[t + 1];  // drop self (rank 0, dist 0)
}

// --- small-level knn (1024/256): proven two-pass chunked ladder ---
template <int N, int CHUNK, int NCH>
__global__ void k_knn_part(const float* __restrict__ v, int* __restrict__ part) {
  __shared__ float4 tile[CHUNK];
  int q = blockIdx.x * 64 + threadIdx.x;
  int ch = blockIdx.y;
  int b = blockIdx.z;
  const float* vb = v + (size_t)b * N * 3;
  int cbase = ch * CHUNK;
  for (int j = threadIdx.x; j < CHUNK; j += 64) {
    int g = cbase + j;
    float x = vb[g * 3 + 0], y = vb[g * 3 + 1], z = vb[g * 3 + 2];
    tile[j] = make_float4(x, y, z, fmaf(x, x, fmaf(y, y, z * z)));
  }
  __syncthreads();
  float xq = vb[q * 3 + 0], yq = vb[q * 3 + 1], zq = vb[q * 3 + 2];
  float sqq = fmaf(xq, xq, fmaf(yq, yq, zq * zq));
  float kd[21];
#pragma unroll
  for (int t = 0; t < 21; t++) kd[t] = 3.4e38f;
  for (int j = 0; j < CHUNK; j += 2) {
    float4 c0 = tile[j], c1 = tile[j + 1];
    float d0 = dist_fma(xq, yq, zq, sqq, c0.x, c0.y, c0.z, c0.w);
    float d1 = dist_fma(xq, yq, zq, sqq, c1.x, c1.y, c1.z, c1.w);
    float lo = fminf(d0, d1), hi = fmaxf(d0, d1);
#pragma unroll
    for (int t = 20; t >= 2; --t)
      kd[t] = fminf(fminf(kd[t], fmaxf(kd[t - 1], lo)), fmaxf(kd[t - 2], hi));
    kd[1] = fminf(fminf(kd[1], fmaxf(kd[0], lo)), hi);
    kd[0] = fminf(kd[0], lo);
  }
  float T = kd[20];
  int cnt = 0;
  int* pb = part + (((size_t)b * NCH + ch) * 21) * N + q;
  for (int j = 0; j < CHUNK; ++j) {
    float4 c = tile[j];
    float d = dist_fma(xq, yq, zq, sqq, c.x, c.y, c.z, c.w);
    if (d <= T && cnt < 21) { pb[(size_t)cnt * N] = cbase + j; cnt++; }
  }
}

template <int N, int NCH>
__global__ void k_knn_merge(const float* __restrict__ v, const int* __restrict__ part,
                            int* __restrict__ nb) {
  __shared__ float sx[N], sy[N], sz[N];   // N<=1024 -> <=12 KB
  int q = blockIdx.x * 64 + threadIdx.x;
  int b = blockIdx.y;
  const float* vb = v + (size_t)b * N * 3;
  for (int j = threadIdx.x; j < N; j += 64) {
    sx[j] = vb[j * 3 + 0];
    sy[j] = vb[j * 3 + 1];
    sz[j] = vb[j * 3 + 2];
  }
  __syncthreads();
  float xq = sx[q], yq = sy[q], zq = sz[q];
  float sqq = fmaf(xq, xq, fmaf(yq, yq, zq * zq));
  float kd[21]; int ki[21];
#pragma unroll
  for (int t = 0; t < 21; t++) { kd[t] = 3.4e38f; ki[t] = 0; }
#pragma unroll 1
  for (int ch = 0; ch < NCH; ch++) {
    // preload the whole chunk's 21 indices (independent loads, one latency)
    int idxs[21];
#pragma unroll
    for (int s = 0; s < 21; s++)
      idxs[s] = part[(((size_t)b * NCH + ch) * 21 + s) * N + q];
    // independent dist computations (LDS reads pipeline)
    float dsv[21];
#pragma unroll
    for (int s = 0; s < 21; s++) {
      int j_ = idxs[s];
      float cx = sx[j_], cy = sy[j_], cz = sz[j_];
      float cw = fmaf(cx, cx, fmaf(cy, cy, cz * cz));
      dsv[s] = dist_fma(xq, yq, zq, sqq, cx, cy, cz, cw);
    }
    // chunk fast path: skip whole insertion pass if none qualify
    float mn = dsv[0];
#pragma unroll
    for (int s = 1; s < 21; s++) mn = fminf(mn, dsv[s]);
    if (mn < kd[20]) {
#pragma unroll
      for (int s = 0; s < 21; s++) {
        float dist = dsv[s];
        int idx = idxs[s];
        KNN_INSERT(dist, idx);
      }
    }
  }
  int* nbq = nb + ((size_t)b * N + q) * NB_K;
#pragma unroll
  for (int t = 0; t < NB_K; t++) nbq[t] = ki[t + 1];
}

// ---------------------------------------------------------------------------
// conv_surface
// ---------------------------------------------------------------------------
__global__ void k_surface(const float* __restrict__ v, const int* __restrict__ nb,
                          const float* __restrict__ dirn, float* __restrict__ out) {
  int idx = blockIdx.x * 64 + threadIdx.x;  // b*4096+n
  int b = idx >> 12, n = idx & 4095;
  const float* vb = v + (size_t)b * 4096 * 3;
  float xq = vb[n * 3 + 0], yq = vb[n * 3 + 1], zq = vb[n * 3 + 2];
  float mx[32];
#pragma unroll
  for (int f = 0; f < 32; f++) mx[f] = 0.0f;
  for (int k = 0; k < NB_K; k++) {
    int j = nb[(size_t)idx * NB_K + k];
    float dx = vb[j * 3 + 0] - xq, dy = vb[j * 3 + 1] - yq, dz = vb[j * 3 + 2] - zq;
    float nr = sqrtf((dx * dx + dy * dy) + dz * dz);
    float inv = 1.0f / fmaxf(nr, 1e-12f);
    dx *= inv; dy *= inv; dz *= inv;
#pragma unroll
    for (int f = 0; f < 32; f++) {
      float th = dx * dirn[f] + dy * dirn[32 + f] + dz * dirn[64 + f];
      th = fmaxf(th, 0.0f);
      mx[f] = fmaxf(mx[f], th);
    }
  }
#pragma unroll
  for (int f = 0; f < 32; f++) out[(size_t)idx * 32 + f] = mx[f];
}

// ---------------------------------------------------------------------------
// Tiled fp32 GEMM, BM=128 BN=64 BK=16, 256 thr, 8x4 per thread.
// Requires M%128==0, N%64==0, K%16==0. Accumulation: acc=bias then k
// ascending -- per-output-element fma chain identical to the 64x64 tile and
// to the reference matmul order (bitwise-stable across tile shapes).
// ---------------------------------------------------------------------------
__global__ void k_gemm_tile128(const float* __restrict__ A, const float* __restrict__ W,
                               const float* __restrict__ bias, float* __restrict__ out,
                               int M, int K, int N) {
  __shared__ float As[16][132];   // [k][m] row stride 528 B (16B-aligned reads)
  __shared__ float Bs[16][68];    // [k][n]
  int m0 = blockIdx.y * 128, n0 = blockIdx.x * 64;
  int t = threadIdx.x;
  int tr = t >> 4, tc = t & 15;       // compute: rows tr*8..+7, cols tc*4..+3
  int ar = t >> 2, ak4 = t & 3;       // A load: rows ar and ar+64, k-quad ak4
  int bk = t >> 4, bn4 = t & 15;      // B load: k-row bk, n-quad bn4
  float acc[8][4];
#pragma unroll
  for (int j = 0; j < 4; j++) {
    float bv = bias ? bias[n0 + tc * 4 + j] : 0.0f;
#pragma unroll
    for (int i = 0; i < 8; i++) acc[i][j] = bv;
  }
  for (int k0 = 0; k0 < K; k0 += 16) {
    float4 av0 = *(const float4*)(A + (size_t)(m0 + ar) * K + k0 + ak4 * 4);
    float4 av1 = *(const float4*)(A + (size_t)(m0 + ar + 64) * K + k0 + ak4 * 4);
    float4 wv  = *(const float4*)(W + (size_t)(k0 + bk) * N + n0 + bn4 * 4);
    __syncthreads();
    As[ak4 * 4 + 0][ar] = av0.x;
    As[ak4 * 4 + 1][ar] = av0.y;
    As[ak4 * 4 + 2][ar] = av0.z;
    As[ak4 * 4 + 3][ar] = av0.w;
    As[ak4 * 4 + 0][ar + 64] = av1.x;
    As[ak4 * 4 + 1][ar + 64] = av1.y;
    As[ak4 * 4 + 2][ar + 64] = av1.z;
    As[ak4 * 4 + 3][ar + 64] = av1.w;
    *(float4*)(&Bs[bk][bn4 * 4]) = wv;
    __syncthreads();
#pragma unroll
    for (int kk = 0; kk < 16; kk++) {
      float a[8], b[4];
#pragma unroll
      for (int i = 0; i < 8; i++) a[i] = As[kk][tr * 8 + i];
#pragma unroll
      for (int j = 0; j < 4; j++) b[j] = Bs[kk][tc * 4 + j];
#pragma unroll
      for (int i = 0; i < 8; i++)
#pragma unroll
        for (int j = 0; j < 4; j++) acc[i][j] = fmaf(a[i], b[j], acc[i][j]);
    }
  }
#pragma unroll
  for (int i = 0; i < 8; i++)
    *(float4*)(out + (size_t)(m0 + tr * 8 + i) * N + n0 + tc * 4) =
        make_float4(acc[i][0], acc[i][1], acc[i][2], acc[i][3]);
}

// 64x64 tile kept for the N=64 cluster GEMM (keeps 2x the blocks in flight).
__global__ void k_gemm_tile(const float* __restrict__ A, const float* __restrict__ W,
                            const float* __restrict__ bias, float* __restrict__ out,
                            int M, int K, int N) {
  __shared__ float As[16][68];
  __shared__ float Bs[16][68];
  int m0 = blockIdx.y * 64, n0 = blockIdx.x * 64;
  int t = threadIdx.x;
  int tr = t >> 4, tc = t & 15;
  int am = t >> 2, ak4 = t & 3;       // A load: row am, k-quad ak4
  int bk = t >> 4, bn4 = t & 15;      // B load: k-row bk, n-quad bn4
  float acc[4][4];
#pragma unroll
  for (int j = 0; j < 4; j++) {
    float bv = bias ? bias[n0 + tc * 4 + j] : 0.0f;
#pragma unroll
    for (int i = 0; i < 4; i++) acc[i][j] = bv;
  }
  for (int k0 = 0; k0 < K; k0 += 16) {
    float4 av = *(const float4*)(A + (size_t)(m0 + am) * K + k0 + ak4 * 4);
    float4 wv = *(const float4*)(W + (size_t)(k0 + bk) * N + n0 + bn4 * 4);
    __syncthreads();
    As[ak4 * 4 + 0][am] = av.x;
    As[ak4 * 4 + 1][am] = av.y;
    As[ak4 * 4 + 2][am] = av.z;
    As[ak4 * 4 + 3][am] = av.w;
    *(float4*)(&Bs[bk][bn4 * 4]) = wv;
    __syncthreads();
#pragma unroll
    for (int kk = 0; kk < 16; kk++) {
      float a[4], b[4];
#pragma unroll
      for (int i = 0; i < 4; i++) a[i] = As[kk][tr * 4 + i];
#pragma unroll
      for (int j = 0; j < 4; j++) b[j] = Bs[kk][tc * 4 + j];
#pragma unroll
      for (int i = 0; i < 4; i++)
#pragma unroll
        for (int j = 0; j < 4; j++) acc[i][j] = fmaf(a[i], b[j], acc[i][j]);
    }
  }
#pragma unroll
  for (int i = 0; i < 4; i++)
    *(float4*)(out + (size_t)(m0 + tr * 4 + i) * N + n0 + tc * 4) =
        make_float4(acc[i][0], acc[i][1], acc[i][2], acc[i][3]);
}

// small-M GEMM (gating, M=8)
template <int K>
__global__ void k_gemm4(const float* __restrict__ A, const float* __restrict__ W,
                        const float* __restrict__ bias, float* __restrict__ out,
                        int R, int C) {
  int idx = blockIdx.x * 256 + threadIdx.x;
  int c4 = C >> 2;
  if (idx >= R * c4) return;
  int r = idx / c4, c = (idx - r * c4) << 2;
  const float* a = A + (size_t)r * K;
  float4 acc;
  if (bias) acc = *(const float4*)(bias + c);
  else acc = make_float4(0.f, 0.f, 0.f, 0.f);
#pragma unroll 8
  for (int k = 0; k < K; k++) {
    float av = a[k];
    float4 wv = *(const float4*)(W + (size_t)k * C + c);
    acc.x = fmaf(av, wv.x, acc.x);
    acc.y = fmaf(av, wv.y, acc.y);
    acc.z = fmaf(av, wv.z, acc.z);
    acc.w = fmaf(av, wv.w, acc.w);
  }
  *(float4*)(out + (size_t)r * C + c) = acc;
}

// ---------------------------------------------------------------------------
// conv_layer combine
// ---------------------------------------------------------------------------
template <int COUT, int CPT, bool RELU>
__global__ void k_combine(const float* __restrict__ v, const int* __restrict__ nb,
                          const float* __restrict__ fo, const float* __restrict__ dirn,
                          float* __restrict__ out, int N) {
  constexpr int THREADS = COUT / CPT;
  int bn = blockIdx.x;
  int b = bn / N, n = bn - b * N;
  __shared__ float ds[NB_K][3];
  __shared__ int nbs[NB_K];
  const float* vb = v + (size_t)b * N * 3;
  if (threadIdx.x < NB_K) {
    int j = nb[(size_t)bn * NB_K + threadIdx.x];
    nbs[threadIdx.x] = j;
    float xq = vb[n * 3 + 0], yq = vb[n * 3 + 1], zq = vb[n * 3 + 2];
    float dx = vb[j * 3 + 0] - xq, dy = vb[j * 3 + 1] - yq, dz = vb[j * 3 + 2] - zq;
    float nr = sqrtf((dx * dx + dy * dy) + dz * dz);
    float inv = 1.0f / fmaxf(nr, 1e-12f);
    ds[threadIdx.x][0] = dx * inv;
    ds[threadIdx.x][1] = dy * inv;
    ds[threadIdx.x][2] = dz * inv;
  }
  __syncthreads();
#pragma unroll
  for (int cc = 0; cc < CPT; cc++) {
    int c = threadIdx.x + cc * THREADS;
    float w0 = dirn[c], w1 = dirn[COUT + c], w2 = dirn[2 * COUT + c];
    float acc = -3.4e38f;
    for (int k = 0; k < NB_K; k++) {
      float th = ds[k][0] * w0 + ds[k][1] * w1 + ds[k][2] * w2;
      th = fmaxf(th, 0.0f);
      float fs = fo[((size_t)b * N + nbs[k]) * (2 * COUT) + COUT + c];
      acc = fmaxf(acc, th * fs);
    }
    float res = fo[(size_t)bn * (2 * COUT) + c] + acc;
    if (RELU) res = fmaxf(res, 0.0f);
    out[(size_t)bn * COUT + c] = res;
  }
}

// ---------------------------------------------------------------------------
// gather-max pooling over neighbors
// ---------------------------------------------------------------------------
template <int C>
__global__ void k_gathermax(const float* __restrict__ fm, const int* __restrict__ nb,
                            float* __restrict__ out, int N) {
  int bn = blockIdx.x;
  int b = bn / N;
  __shared__ int nbs[NB_K];
  if (threadIdx.x < NB_K) nbs[threadIdx.x] = nb[(size_t)bn * NB_K + threadIdx.x];
  __syncthreads();
  int c = threadIdx.x;
  float acc = -3.4e38f;
  for (int k = 0; k < NB_K; k++)
    acc = fmaxf(acc, fm[((size_t)b * N + nbs[k]) * C + c]);
  out[(size_t)bn * C + c] = acc;
}

// ---------------------------------------------------------------------------
// pool-index gather
// ---------------------------------------------------------------------------
__global__ void k_poolgather(const float* __restrict__ in, const int* __restrict__ pool,
                             float* __restrict__ out, int n_in, int n_out, int C) {
  int idx = blockIdx.x * 256 + threadIdx.x;
  if (idx >= 8 * n_out * C) return;
  int c = idx % C; int t = idx / C; int i = t % n_out; int b = t / n_out;
  out[idx] = in[((size_t)b * n_in + pool[i]) * C + c];
}

// ---------------------------------------------------------------------------
// GeM pooling, n-split 4-way (32 -> 512 waves). Partial sums combined in
// fixed order ((p0+p1)+p2)+p3 -- deterministic, ~1e-7 rel vs serial order.
// ---------------------------------------------------------------------------
__global__ void k_gem(const float* __restrict__ fm4, const float* __restrict__ gp,
                      float* __restrict__ y) {
  __shared__ float red[4][64];
  int blk = blockIdx.x;            // 8*16 = 128 blocks
  int b = blk >> 4, f0 = (blk & 15) << 6;
  int fl = threadIdx.x & 63, ng = threadIdx.x >> 6;
  int f = f0 + fl;
  float p = gp[0];
  float s = 0.0f;
  const float* base = fm4 + (size_t)b * 256 * 1024 + f;
  if (p == 3.0f) {
    for (int n = ng * 64; n < ng * 64 + 64; n++) {
      float val = fmaxf(base[(size_t)n * 1024], 1e-6f);
      s += val * val * val;
    }
  } else {
    for (int n = ng * 64; n < ng * 64 + 64; n++) {
      float val = fmaxf(base[(size_t)n * 1024], 1e-6f);
      s += powf(val, p);
    }
  }
  red[ng][fl] = s;
  __syncthreads();
  if (ng == 0) {
    float st = ((red[0][fl] + red[1][fl]) + red[2][fl]) + red[3][fl];
    y[b * 1024 + f] = powf(st * (1.0f / 256.0f), 1.0f / p);
  }
}

// ---------------------------------------------------------------------------
// NetVLAD pieces
// ---------------------------------------------------------------------------
__global__ void k_bnstats(const float* __restrict__ x, int R, int C,
                          float* __restrict__ mean, float* __restrict__ rstd) {
  int c = blockIdx.x;
  __shared__ float red[256];
  float s = 0.0f;
  for (int r = threadIdx.x; r < R; r += 256) s += x[(size_t)r * C + c];
  red[threadIdx.x] = s; __syncthreads();
  for (int st = 128; st > 0; st >>= 1) {
    if (threadIdx.x < st) red[threadIdx.x] += red[threadIdx.x + st];
    __syncthreads();
  }
  float m = red[0] / (float)R;
  __syncthreads();
  float s2 = 0.0f;
  for (int r = threadIdx.x; r < R; r += 256) {
    float d = x[(size_t)r * C + c] - m; s2 += d * d;
  }
  red[threadIdx.x] = s2; __syncthreads();
  for (int st = 128; st > 0; st >>= 1) {
    if (threadIdx.x < st) red[threadIdx.x] += red[threadIdx.x + st];
    __syncthreads();
  }
  if (threadIdx.x == 0) {
    mean[c] = m;
    rstd[c] = 1.0f / sqrtf(red[0] / (float)R + BN_EPS);
  }
}

__global__ void k_softmax(const float* __restrict__ a0, const float* __restrict__ mean,
                          const float* __restrict__ rstd, const float* __restrict__ g,
                          const float* __restrict__ bb, float* __restrict__ act) {
  int r = blockIdx.x, c = threadIdx.x;
  float x = (a0[(size_t)r * 64 + c] - mean[c]) * rstd[c] * g[c] + bb[c];
  float mx = x;
  for (int off = 32; off > 0; off >>= 1) mx = fmaxf(mx, __shfl_xor(mx, off));
  float e = expf(x - mx);
  float sm = e;
  for (int off = 32; off > 0; off >>= 1) sm += __shfl_xor(sm, off);
  act[(size_t)r * 64 + c] = e / sm;
}

// m-split 4-way (8 -> 32 waves); ordered partial combine.
__global__ void k_colsum(const float* __restrict__ act, float* __restrict__ asum) {
  __shared__ float red[4][64];
  int b = blockIdx.x;
  int k = threadIdx.x & 63, mg = threadIdx.x >> 6;
  float s = 0.0f;
  for (int m = mg * 64; m < mg * 64 + 64; m++) s += act[((size_t)b * 256 + m) * 64 + k];
  red[mg][k] = s;
  __syncthreads();
  if (mg == 0)
    asum[b * 64 + k] = ((red[0][k] + red[1][k]) + red[2][k]) + red[3][k];
}

// vlad[b,f,k] = sum_m xv[b,m,f]*act[b,m,k] - asum[b,k]*cw2[f,k]
// tiled: block (f-tile 64 x k 64), LDS-staged, 4x4 per thread
__global__ void k_vlad_tile(const float* __restrict__ act, const float* __restrict__ xv,
                            const float* __restrict__ asum, const float* __restrict__ cw2,
                            float* __restrict__ vlad) {
  __shared__ float Xs[64][68];   // [m][f]
  __shared__ float Ac[64][68];   // [m][k]
  int b = blockIdx.y, f0 = blockIdx.x * 64;
  int t = threadIdx.x, tr = t >> 4, tc = t & 15;
  float acc[4][4] = {};
  for (int m0 = 0; m0 < 256; m0 += 64) {
    __syncthreads();
#pragma unroll
    for (int r = 0; r < 4; r++) {
      int m = r * 16 + (t >> 4);
      *(float4*)(&Xs[m][(t & 15) * 4]) =
          *(const float4*)(xv + ((size_t)b * 256 + m0 + m) * 1024 + f0 + (t & 15) * 4);
      *(float4*)(&Ac[m][(t & 15) * 4]) =
          *(const float4*)(act + ((size_t)b * 256 + m0 + m) * 64 + (t & 15) * 4);
    }
    __syncthreads();
    for (int mm = 0; mm < 64; mm++) {
      float a[4], c[4];
#pragma unroll
      for (int i = 0; i < 4; i++) a[i] = Xs[mm][tr * 4 + i];
#pragma unroll
      for (int j = 0; j < 4; j++) c[j] = Ac[mm][tc * 4 + j];
#pragma unroll
      for (int i = 0; i < 4; i++)
#pragma unroll
        for (int j = 0; j < 4; j++) acc[i][j] = fmaf(a[i], c[j], acc[i][j]);
    }
  }
#pragma unroll
  for (int i = 0; i < 4; i++) {
    int f = f0 + tr * 4 + i;
#pragma unroll
    for (int j = 0; j < 4; j++) {
      int k = tc * 4 + j;
      vlad[((size_t)b * 1024 + f) * 64 + k] = acc[i][j] - asum[b * 64 + k] * cw2[f * 64 + k];
    }
  }
}

__global__ void k_norm1(const float* __restrict__ vlad, float* __restrict__ scale1) {
  int bk = blockIdx.x;  // b*64+k
  int b = bk >> 6, k = bk & 63;
  float s = 0.0f;
  for (int f = threadIdx.x; f < 1024; f += 64) {
    float val = vlad[((size_t)b * 1024 + f) * 64 + k];
    s += val * val;
  }
  for (int off = 32; off > 0; off >>= 1) s += __shfl_xor(s, off);
  if (threadIdx.x == 0) scale1[bk] = 1.0f / fmaxf(sqrtf(s), 1e-12f);
}

__global__ void k_norm2(const float* __restrict__ vlad, const float* __restrict__ scale1,
                        float* __restrict__ scale2) {
  int b = blockIdx.x;
  __shared__ float red[256];
  float s = 0.0f;
  for (int i = threadIdx.x; i < 65536; i += 256) {
    float val = vlad[(size_t)b * 65536 + i] * scale1[b * 64 + (i & 63)];
    s += val * val;
  }
  red[threadIdx.x] = s; __syncthreads();
  for (int st = 128; st > 0; st >>= 1) {
    if (threadIdx.x < st) red[threadIdx.x] += red[threadIdx.x + st];
    __syncthreads();
  }
  if (threadIdx.x == 0) scale2[b] = 1.0f / fmaxf(sqrtf(red[0]), 1e-12f);
}

__global__ void k_vscale(float* __restrict__ vlad, const float* __restrict__ scale1,
                         const float* __restrict__ scale2) {
  int idx = blockIdx.x * 256 + threadIdx.x;
  int b = idx >> 16; int r = idx & 65535;
  vlad[idx] = vlad[idx] * scale1[b * 64 + (r & 63)] * scale2[b];
}

__global__ void k_hidden_partial(const float* __restrict__ vlad, const float* __restrict__ hw,
                                 float* __restrict__ partial) {
  __shared__ float vs[8][512];
  int cg = blockIdx.x;   // 0..3
  int kb = blockIdx.y;   // 0..127
  int col = cg * 256 + threadIdx.x;
  int k0 = kb * 512;
  for (int i = threadIdx.x; i < 8 * 512; i += 256) {
    int b = i >> 9, k = i & 511;
    vs[b][k] = vlad[(size_t)b * 65536 + k0 + k];
  }
  __syncthreads();
  float acc[8] = {0, 0, 0, 0, 0, 0, 0, 0};
  for (int k = 0; k < 512; k++) {
    float w = hw[(size_t)(k0 + k) * 1024 + col];
#pragma unroll
    for (int b = 0; b < 8; b++) acc[b] += vs[b][k] * w;
  }
#pragma unroll
  for (int b = 0; b < 8; b++)
    partial[((size_t)kb * 8 + b) * 1024 + col] = acc[b];
}

__global__ void k_hidden_reduce(const float* __restrict__ partial, float* __restrict__ hid) {
  int idx = blockIdx.x * 256 + threadIdx.x;  // b*1024+c
  int b = idx >> 10, c = idx & 1023;
  float s = 0.0f;
  for (int kb = 0; kb < 128; kb++) s += partial[((size_t)kb * 8 + b) * 1024 + c];
  hid[idx] = s;
}

__global__ void k_bn8(const float* __restrict__ x, const float* __restrict__ g,
                      const float* __restrict__ bb, float* __restrict__ out) {
  int c = blockIdx.x * 256 + threadIdx.x;
  if (c >= 1024) return;
  float v[8]; float s = 0.0f;
#pragma unroll
  for (int b = 0; b < 8; b++) { v[b] = x[b * 1024 + c]; s += v[b]; }
  float m = s * 0.125f; float s2 = 0.0f;
#pragma unroll
  for (int b = 0; b < 8; b++) { float d = v[b] - m; s2 += d * d; }
  float rstd = 1.0f / sqrtf(s2 * 0.125f + BN_EPS);
#pragma unroll
  for (int b = 0; b < 8; b++) out[b * 1024 + c] = (v[b] - m) * rstd * g[c] + bb[c];
}

__global__ void k_gbn_out(const float* __restrict__ gat, const float* __restrict__ g,
                          const float* __restrict__ bb, const float* __restrict__ vladbn,
                          float* __restrict__ desc) {
  int c = blockIdx.x * 256 + threadIdx.x;
  if (c >= 1024) return;
  float v[8]; float s = 0.0f;
#pragma unroll
  for (int b = 0; b < 8; b++) { v[b] = gat[b * 1024 + c]; s += v[b]; }
  float m = s * 0.125f; float s2 = 0.0f;
#pragma unroll
  for (int b = 0; b < 8; b++) { float d = v[b] - m; s2 += d * d; }
  float rstd = 1.0f / sqrtf(s2 * 0.125f + BN_EPS);
#pragma unroll
  for (int b = 0; b < 8; b++) {
    float x = (v[b] - m) * rstd * g[c] + bb[c];
    float gate = 1.0f / (1.0f + expf(-x));
    desc[b * 1024 + c] = vladbn[b * 1024 + c] * gate;
  }
}

// ---------------------------------------------------------------------------
// launch
// ---------------------------------------------------------------------------
extern "C" void kernel_launch(void* const* d_in, const int* in_sizes, int n_in,
                              void* d_out, int out_size, void* d_ws, size_t ws_size,
                              hipStream_t stream) {
  (void)in_sizes; (void)n_in; (void)out_size; (void)ws_size;
  const float* x    = (const float*)d_in[0];
  const float* dir0 = (const float*)d_in[1];
  const float* W1   = (const float*)d_in[2];
  const float* b1   = (const float*)d_in[3];
  const float* dir1 = (const float*)d_in[4];
  const float* W2   = (const float*)d_in[5];
  const float* b2   = (const float*)d_in[6];
  const float* dir2 = (const float*)d_in[7];
  const float* W3   = (const float*)d_in[8];
  const float* b3   = (const float*)d_in[9];
  const float* dir3 = (const float*)d_in[10];
  const float* W4   = (const float*)d_in[11];
  const float* b4   = (const float*)d_in[12];
  const float* dir4 = (const float*)d_in[13];
  const float* gemp = (const float*)d_in[14];
  const float* cw   = (const float*)d_in[15];
  const float* cw2  = (const float*)d_in[16];
  const float* hw   = (const float*)d_in[17];
  const float* bn1g = (const float*)d_in[18];
  const float* bn1b = (const float*)d_in[19];
  const float* bn2g = (const float*)d_in[20];
  const float* bn2b = (const float*)d_in[21];
  const float* gw   = (const float*)d_in[22];
  const float* gbng = (const float*)d_in[23];
  const float* gbnb = (const float*)d_in[24];
  float* out = (float*)d_out;
  char* ws = (char*)d_ws;

  float* F_DIRN0 = (float*)(ws + OFF_DIRN0);
  float* F_DIRN1 = (float*)(ws + OFF_DIRN1);
  float* F_DIRN2 = (float*)(ws + OFF_DIRN2);
  float* F_DIRN3 = (float*)(ws + OFF_DIRN3);
  float* F_DIRN4 = (float*)(ws + OFF_DIRN4);
  int*   I_POOL1 = (int*)(ws + OFF_POOL1);
  int*   I_POOL2 = (int*)(ws + OFF_POOL2);
  int*   I_NB    = (int*)(ws + OFF_NB);
  int*   I_KPART = (int*)(ws + OFF_KPART);
  unsigned short* U_KSURV = (unsigned short*)(ws + OFF_KSURV);
  int*   I_KCNT  = (int*)(ws + OFF_KCNT);
  float* F_KT0   = (float*)(ws + OFF_KT0);
  float* F_V2    = (float*)(ws + OFF_V2);
  float* F_V3    = (float*)(ws + OFF_V3);
  float* F_X1    = (float*)(ws + OFF_X1);
  float* F_X2    = (float*)(ws + OFF_X2);
  float* F_X3    = (float*)(ws + OFF_X3);
  float* F_X4    = (float*)(ws + OFF_X4);

  hipMemcpyAsync(I_POOL1, g_pools.p1, sizeof(g_pools.p1), hipMemcpyHostToDevice, stream);
  hipMemcpyAsync(I_POOL2, g_pools.p2, sizeof(g_pools.p2), hipMemcpyHostToDevice, stream);

  k_dirnorm<<<6, 256, 0, stream>>>(dir0, dir1, dir2, dir3, dir4,
                                   F_DIRN0, F_DIRN1, F_DIRN2, F_DIRN3, F_DIRN4);

  // ---- level 0: 4096 pts (sample -> filter -> merge) ----
  k_knn_sample<4096, 512><<<dim3(64, 8), 64, 0, stream>>>(x, F_KT0);
  k_knn_filter<4096, 512, 8, 64><<<dim3(64, 8, 8), 64, 0, stream>>>(x, F_KT0, U_KSURV, I_KCNT);
  k_knn_merge2<4096, 8, 64><<<dim3(64, 8), 64, 0, stream>>>(x, U_KSURV, I_KCNT, I_NB);
  k_surface<<<512, 64, 0, stream>>>(x, I_NB, F_DIRN0, F_X3);
  k_gemm_tile128<<<dim3(2, 256), 256, 0, stream>>>(F_X3, W1, b1, F_X1, 32768, 32, 128);
  k_combine<64, 1, true><<<32768, 64, 0, stream>>>(x, I_NB, F_X1, F_DIRN1, F_X4, 4096);
  k_gathermax<64><<<32768, 64, 0, stream>>>(F_X4, I_NB, F_X2, 4096);
  k_poolgather<<<(8 * 1024 * 3 + 255) / 256, 256, 0, stream>>>(x, I_POOL1, F_V2, 4096, 1024, 3);
  k_poolgather<<<(8 * 1024 * 64 + 255) / 256, 256, 0, stream>>>(F_X2, I_POOL1, F_X3, 4096, 1024, 64);

  // ---- level 1: 1024 pts ----
  k_knn_part<1024, 128, 8><<<dim3(16, 8, 8), 64, 0, stream>>>(F_V2, I_KPART);
  k_knn_merge<1024, 8><<<dim3(16, 8), 64, 0, stream>>>(F_V2, I_KPART, I_NB);
  k_gemm_tile128<<<dim3(4, 64), 256, 0, stream>>>(F_X3, W2, b2, F_X4, 8192, 64, 256);
  k_combine<128, 1, true><<<8192, 128, 0, stream>>>(F_V2, I_NB, F_X4, F_DIRN2, F_X1, 1024);
  k_gemm_tile128<<<dim3(8, 64), 256, 0, stream>>>(F_X1, W3, b3, F_X2, 8192, 128, 512);
  k_combine<256, 1, true><<<8192, 256, 0, stream>>>(F_V2, I_NB, F_X2, F_DIRN3, F_X4, 1024);
  k_gathermax<256><<<8192, 256, 0, stream>>>(F_X4, I_NB, F_X1, 1024);
  k_poolgather<<<(8 * 256 * 3 + 255) / 256, 256, 0, stream>>>(F_V2, I_POOL2, F_V3, 1024, 256, 3);
  k_poolgather<<<(8 * 256 * 256 + 255) / 256, 256, 0, stream>>>(F_X1, I_POOL2, F_X3, 1024, 256, 256);

  // ---- level 2: 256 pts ----
  k_knn_part<256, 64, 4><<<dim3(4, 4, 8), 64, 0, stream>>>(F_V3, I_KPART);
  k_knn_merge<256, 4><<<dim3(4, 8), 64, 0, stream>>>(F_V3, I_KPART, I_NB);
  k_gemm_tile128<<<dim3(32, 16), 256, 0, stream>>>(F_X3, W4, b4, F_X2, 2048, 256, 2048);
  k_combine<1024, 4, false><<<2048, 256, 0, stream>>>(F_V3, I_NB, F_X2, F_DIRN4, F_X4, 256);

  // ---- GeM head -> out[0:8192] ----
  k_gem<<<128, 256, 0, stream>>>(F_X4, gemp, out);

  // ---- NetVLAD head -> out[8192:16384] ----
  float* F_ACT0 = (float*)(ws + OFF_ACT0);
  float* F_ACT  = (float*)(ws + OFF_ACT);
  float* F_VLAD = (float*)(ws + OFF_VLAD);
  float* F_PART = (float*)(ws + OFF_PART);
  float* F_BN1M = (float*)(ws + OFF_BN1M);
  float* F_BN1R = (float*)(ws + OFF_BN1R);
  float* F_ASUM = (float*)(ws + OFF_ASUM);
  float* F_SC1  = (float*)(ws + OFF_SCALE1);
  float* F_SC2  = (float*)(ws + OFF_SCALE2);
  float* F_HID  = (float*)(ws + OFF_HID);
  float* F_VBN  = (float*)(ws + OFF_VLADBN);
  float* F_GAT  = (float*)(ws + OFF_GAT);

  k_gemm_tile<<<dim3(1, 32), 256, 0, stream>>>(F_X4, cw, nullptr, F_ACT0, 2048, 1024, 64);
  k_bnstats<<<64, 256, 0, stream>>>(F_ACT0, 2048, 64, F_BN1M, F_BN1R);
  k_softmax<<<2048, 64, 0, stream>>>(F_ACT0, F_BN1M, F_BN1R, bn1g, bn1b, F_ACT);
  k_colsum<<<8, 256, 0, stream>>>(F_ACT, F_ASUM);
  k_vlad_tile<<<dim3(16, 8), 256, 0, stream>>>(F_ACT, F_X4, F_ASUM, cw2, F_VLAD);
  k_norm1<<<512, 64, 0, stream>>>(F_VLAD, F_SC1);
  k_norm2<<<8, 256, 0, stream>>>(F_VLAD, F_SC1, F_SC2);
  k_vscale<<<(8 * 65536) / 256, 256, 0, stream>>>(F_VLAD, F_SC1, F_SC2);
  k_hidden_partial<<<dim3(4, 128), 256, 0, stream>>>(F_VLAD, hw, F_PART);
  k_hidden_reduce<<<32, 256, 0, stream>>>(F_PART, F_HID);
  k_bn8<<<4, 256, 0, stream>>>(F_HID, bn2g, bn2b, F_VBN);
  k_gemm4<1024><<<(8 * 256 + 255) / 256, 256, 0, stream>>>(F_VBN, gw, nullptr, F_GAT, 8, 1024);
  k_gbn_out<<<4, 256, 0, stream>>>(F_GAT, gbng, gbnb, F_VBN, out + 8192);
}

// Round 7
// 1269.087 us; speedup vs baseline: 1.0791x; 1.0282x over previous
//
#include <hip/hip_runtime.h>
#include <math.h>

// ============================================================================
// SBDD point-cloud network, fp32, bs=8, N_PTS=4096, NB=20, S=1.
// R1: LDS-stage coordinates in kNN merge kernels.
// R2: break survivor-index load serialization (filter pads to x4 sentinels,
//     merge2 4-deep index prefetch, small merges preload 21 idx).
// R3: 128x64 fp32 GEMM tile; kNN insert group-skip; 8-deep prefetch.
// R4: k_gem / k_colsum reduction split 4-way (ordered partial combine).
// R6: kNN merges 2-WAVES-PER-BLOCK (same grid, 128 thr): wave h scans chunk
//     half h for 64 distinct queries (full coalescing, unlike R4's lane-pair
//     split), wave1 parks its sorted-21 in LDS, wave0 merges (ascending,
//     strict < -- tie-stable: half0 indices all < half1 indices).
// R7: identical resubmission of R6 (container-level infra failure, no data).
// ============================================================================

#define NB_K 20
#define BN_EPS 1e-5f

// ---------------------------------------------------------------------------
// Host-side reproduction of np.random.RandomState(seed).permutation(n)
// ---------------------------------------------------------------------------
namespace {
struct MT19937H {
  unsigned mt[624]; int pos;
  void seed(unsigned s) {
    for (int i = 0; i < 624; i++) { mt[i] = s; s = 1812433253u * (s ^ (s >> 30)) + (unsigned)i + 1u; }
    pos = 624;
  }
  unsigned next() {
    if (pos >= 624) {
      for (int i = 0; i < 624; i++) {
        unsigned y = (mt[i] & 0x80000000u) | (mt[(i + 1) % 624] & 0x7fffffffu);
        unsigned v = mt[(i + 397) % 624] ^ (y >> 1);
        if (y & 1u) v ^= 0x9908b0dfu;
        mt[i] = v;
      }
      pos = 0;
    }
    unsigned y = mt[pos++];
    y ^= y >> 11; y ^= (y << 7) & 0x9d2c5680u; y ^= (y << 15) & 0xefc60000u; y ^= y >> 18;
    return y;
  }
  unsigned interval(unsigned mx) {
    if (mx == 0) return 0;
    unsigned mask = mx;
    mask |= mask >> 1; mask |= mask >> 2; mask |= mask >> 4; mask |= mask >> 8; mask |= mask >> 16;
    unsigned v;
    do { v = next() & mask; } while (v > mx);
    return v;
  }
};
struct Pools {
  int p1[1024];
  int p2[256];
  int arr[4096];
  Pools() {
    MT19937H m;
    m.seed(1);
    for (int i = 0; i < 4096; i++) arr[i] = i;
    for (int i = 4095; i >= 1; i--) {
      int j = (int)m.interval((unsigned)i);
      int t = arr[j]; arr[j] = arr[i]; arr[i] = t;
    }
    for (int i = 0; i < 1024; i++) p1[i] = arr[i];
    m.seed(2);
    for (int i = 0; i < 1024; i++) arr[i] = i;
    for (int i = 1023; i >= 1; i--) {
      int j = (int)m.interval((unsigned)i);
      int t = arr[j]; arr[j] = arr[i]; arr[i] = t;
    }
    for (int i = 0; i < 256; i++) p2[i] = arr[i];
  }
};
Pools g_pools;
}

// ---------------------------------------------------------------------------
// Workspace layout (bytes).
// ---------------------------------------------------------------------------
#define OFF_POOL1   (0u)
#define OFF_POOL2   (16u << 10)
#define OFF_DIRN0   (32u << 10)
#define OFF_DIRN1   (36u << 10)
#define OFF_DIRN2   (40u << 10)
#define OFF_DIRN3   (48u << 10)
#define OFF_DIRN4   (56u << 10)
#define OFF_V2      (128u << 10)
#define OFF_V3      (256u << 10)
#define OFF_BN1M    (288u << 10)
#define OFF_BN1R    (292u << 10)
#define OFF_ASUM    (296u << 10)
#define OFF_SCALE1  (304u << 10)
#define OFF_SCALE2  (312u << 10)
#define OFF_HID     (320u << 10)
#define OFF_VLADBN  (352u << 10)
#define OFF_GAT     (384u << 10)
#define OFF_NB      (1u << 20)          // neighbor idx, reused all stages
#define OFF_X1      (4u << 20)          // 16 MB
#define OFF_X2      (20u << 20)         // 16 MB
#define OFF_X3      (36u << 20)         // 8 MB
#define OFF_X4      (44u << 20)         // 8 MB
// knn4096 scratch (X regions free during knn): surv 32MB @X1, cnt 1MB @X3, T0 @X4
#define OFF_KSURV   (OFF_X1)
#define OFF_KCNT    (OFF_X3)
#define OFF_KT0     (OFF_X4)
#define OFF_KPART   (OFF_X1)            // small-level knn partials
#define OFF_ACT0    (OFF_X1)
#define OFF_ACT     (OFF_X1 + (1u << 20))
#define OFF_VLAD    (OFF_X1 + (2u << 20))
#define OFF_PART    (OFF_X1 + (8u << 20))

// ---------------------------------------------------------------------------
// dir normalization: l2norm(dirs, axis=0)
// ---------------------------------------------------------------------------
__global__ void k_dirnorm(const float* __restrict__ d0, const float* __restrict__ d1,
                          const float* __restrict__ d2, const float* __restrict__ d3,
                          const float* __restrict__ d4,
                          float* __restrict__ o0, float* __restrict__ o1,
                          float* __restrict__ o2, float* __restrict__ o3,
                          float* __restrict__ o4) {
  int i = blockIdx.x * 256 + threadIdx.x;
  const float* src; float* dst; int F, c;
  if      (i < 32)   { src = d0; dst = o0; F = 32;   c = i; }
  else if (i < 96)   { src = d1; dst = o1; F = 64;   c = i - 32; }
  else if (i < 224)  { src = d2; dst = o2; F = 128;  c = i - 96; }
  else if (i < 480)  { src = d3; dst = o3; F = 256;  c = i - 224; }
  else if (i < 1504) { src = d4; dst = o4; F = 1024; c = i - 480; }
  else return;
  float a = src[c], b = src[F + c], cc = src[2 * F + c];
  float nr = sqrtf((a * a + b * b) + cc * cc);
  float inv = 1.0f / fmaxf(nr, 1e-12f);
  dst[c] = a * inv; dst[F + c] = b * inv; dst[2 * F + c] = cc * inv;
}

// ---------------------------------------------------------------------------
// kNN. dist via fixed fma chain so all kernels agree bitwise; self-dist == 0.
// ---------------------------------------------------------------------------
__device__ __forceinline__ float dist_fma(float xq, float yq, float zq, float sqq,
                                          float cx, float cy, float cz, float cw) {
  float dot = fmaf(xq, cx, fmaf(yq, cy, zq * cz));
  return fmaf(-2.0f, dot, sqq + cw);
}

// insertion into sorted 21-deep (dist,idx) list; strict < keeps stable
// lowest-index-first tie order identical to jax.lax.top_k.
#define KNN_INSERT(DIST, IDX)                                                 \
  if ((DIST) < kd[20]) {                                                      \
    _Pragma("unroll")                                                         \
    for (int t_ = 20; t_ >= 1; t_--) {                                        \
      bool shift_ = (DIST) < kd[t_ - 1];                                      \
      float nk_ = shift_ ? kd[t_ - 1] : (DIST);                               \
      int   ni_ = shift_ ? ki[t_ - 1] : (IDX);                                \
      bool upd_ = (DIST) < kd[t_];                                            \
      if (upd_) { kd[t_] = nk_; ki[t_] = ni_; }                               \
    }                                                                         \
    if ((DIST) < kd[0]) { kd[0] = (DIST); ki[0] = (IDX); }                    \
  }

// --- knn4096 scheme: sample (exact 21st of first 512) -> filter -> merge ---
template <int N, int SAMPLE>
__global__ void k_knn_sample(const float* __restrict__ v, float* __restrict__ T0) {
  __shared__ float4 tile[SAMPLE];
  int q = blockIdx.x * 64 + threadIdx.x;
  int b = blockIdx.y;
  const float* vb = v + (size_t)b * N * 3;
  for (int j = threadIdx.x; j < SAMPLE; j += 64) {
    float x = vb[j * 3 + 0], y = vb[j * 3 + 1], z = vb[j * 3 + 2];
    tile[j] = make_float4(x, y, z, fmaf(x, x, fmaf(y, y, z * z)));
  }
  __syncthreads();
  float xq = vb[q * 3 + 0], yq = vb[q * 3 + 1], zq = vb[q * 3 + 2];
  float sqq = fmaf(xq, xq, fmaf(yq, yq, zq * zq));
  float kd[21];
#pragma unroll
  for (int t = 0; t < 21; t++) kd[t] = 3.4e38f;
  for (int j = 0; j < SAMPLE; j += 2) {
    float4 c0 = tile[j], c1 = tile[j + 1];
    float d0 = dist_fma(xq, yq, zq, sqq, c0.x, c0.y, c0.z, c0.w);
    float d1 = dist_fma(xq, yq, zq, sqq, c1.x, c1.y, c1.z, c1.w);
    float lo = fminf(d0, d1), hi = fmaxf(d0, d1);
#pragma unroll
    for (int t = 20; t >= 2; --t)
      kd[t] = fminf(fminf(kd[t], fmaxf(kd[t - 1], lo)), fmaxf(kd[t - 2], hi));
    kd[1] = fminf(fminf(kd[1], fmaxf(kd[0], lo)), hi);
    kd[0] = fminf(kd[0], lo);
  }
  T0[(size_t)b * N + q] = kd[20];  // >= global 21st-smallest (sample superset bound)
}

template <int N, int CHUNK, int NCH, int SLOTS>
__global__ void k_knn_filter(const float* __restrict__ v, const float* __restrict__ T0,
                             unsigned short* __restrict__ surv, int* __restrict__ cnt) {
  __shared__ float4 tile[CHUNK];
  int q = blockIdx.x * 64 + threadIdx.x;
  int ch = blockIdx.y;
  int b = blockIdx.z;
  const float* vb = v + (size_t)b * N * 3;
  int cbase = ch * CHUNK;
  for (int j = threadIdx.x; j < CHUNK; j += 64) {
    int g = cbase + j;
    float x = vb[g * 3 + 0], y = vb[g * 3 + 1], z = vb[g * 3 + 2];
    tile[j] = make_float4(x, y, z, fmaf(x, x, fmaf(y, y, z * z)));
  }
  __syncthreads();
  float xq = vb[q * 3 + 0], yq = vb[q * 3 + 1], zq = vb[q * 3 + 2];
  float sqq = fmaf(xq, xq, fmaf(yq, yq, zq * zq));
  float T = T0[(size_t)b * N + q];
  int c = 0;
  unsigned short* sb = surv + ((size_t)b * NCH + ch) * SLOTS * N + q;
  for (int j = 0; j < CHUNK; ++j) {
    float4 cd = tile[j];
    float d = dist_fma(xq, yq, zq, sqq, cd.x, cd.y, cd.z, cd.w);
    if (d <= T && c < SLOTS) {
      sb[(size_t)c * N] = (unsigned short)(cbase + j);
      c++;
    }
  }
  // pad to multiple of 4 with sentinels so merge can run uniform 4-groups
  while (c & 3) { sb[(size_t)c * N] = 0xFFFFu; c++; }
  cnt[((size_t)b * NCH + ch) * N + q] = c;
}

// merge, 2 waves per block (128 thr, grid unchanged): wave h scans chunks
// [h*NCH/2, (h+1)*NCH/2) for 64 DISTINCT queries (full survivor-load
// coalescing -- R4's lane-pair split halved it). Wave1 parks its sorted-21
// in LDS; wave0 inserts it ascending with strict < (tie-stable: half0
// candidate indices all < half1's, matching jax.lax.top_k index order).
// Coord staging traffic unchanged (same block count); waves/CU 2 -> 4.
template <int N, int NCH, int SLOTS>
__global__ void k_knn_merge2(const float* __restrict__ v, const unsigned short* __restrict__ surv,
                             const int* __restrict__ cnt, int* __restrict__ nb) {
  __shared__ float sx[N], sy[N], sz[N];   // N=4096 -> 48 KB
  __shared__ float md[64][21];            // wave1's sorted dists (10.5 KB total)
  __shared__ int   mi[64][21];
  int t = threadIdx.x;                    // 0..127
  int b = blockIdx.y;
  const float* vb = v + (size_t)b * N * 3;
  for (int j = t; j < N; j += 128) {
    sx[j] = vb[j * 3 + 0];
    sy[j] = vb[j * 3 + 1];
    sz[j] = vb[j * 3 + 2];
  }
  __syncthreads();
  int lane = t & 63;
  int wv = t >> 6;                        // wave 0 or 1 (wave-uniform)
  int q = blockIdx.x * 64 + lane;
  float xq = sx[q], yq = sy[q], zq = sz[q];
  float sqq = fmaf(xq, xq, fmaf(yq, yq, zq * zq));
  constexpr int HCH = NCH / 2;
  int ch0 = wv * HCH;
  // hoist this wave's chunk counts (HCH independent loads, one latency)
  int cns[HCH];
#pragma unroll
  for (int c = 0; c < HCH; c++) cns[c] = cnt[((size_t)b * NCH + ch0 + c) * N + q];
  float kd[21]; int ki[21];
#pragma unroll
  for (int t2 = 0; t2 < 21; t2++) { kd[t2] = 3.4e38f; ki[t2] = 0; }
#pragma unroll 1
  for (int cc = 0; cc < HCH; cc++) {
    int cn = cns[cc];                    // multiple of 4 (filter pads)
    const unsigned short* sb = surv + ((size_t)b * NCH + ch0 + cc) * SLOTS * N + q;
    int ia0 = 0xFFFF, ia1 = 0xFFFF, ia2 = 0xFFFF, ia3 = 0xFFFF;
    int ib0 = 0xFFFF, ib1 = 0xFFFF, ib2 = 0xFFFF, ib3 = 0xFFFF;
    if (cn > 0) {
      ia0 = sb[0];
      ia1 = sb[(size_t)1 * N];
      ia2 = sb[(size_t)2 * N];
      ia3 = sb[(size_t)3 * N];
    }
    if (cn > 4) {
      ib0 = sb[(size_t)4 * N];
      ib1 = sb[(size_t)5 * N];
      ib2 = sb[(size_t)6 * N];
      ib3 = sb[(size_t)7 * N];
    }
#pragma unroll 1
    for (int s = 0; s < cn; s += 4) {
      int n0 = 0xFFFF, n1 = 0xFFFF, n2 = 0xFFFF, n3 = 0xFFFF;
      if (s + 8 < cn) {
        n0 = sb[(size_t)(s + 8) * N];
        n1 = sb[(size_t)(s + 9) * N];
        n2 = sb[(size_t)(s + 10) * N];
        n3 = sb[(size_t)(s + 11) * N];
      }
      // 4 independent dist computations (LDS reads pipeline)
      float d0, d1, d2, d3;
      {
        int j_ = ia0 & (N - 1);
        float cx = sx[j_], cy = sy[j_], cz = sz[j_];
        float cw = fmaf(cx, cx, fmaf(cy, cy, cz * cz));
        d0 = (ia0 >= N) ? 3.4e38f : dist_fma(xq, yq, zq, sqq, cx, cy, cz, cw);
      }
      {
        int j_ = ia1 & (N - 1);
        float cx = sx[j_], cy = sy[j_], cz = sz[j_];
        float cw = fmaf(cx, cx, fmaf(cy, cy, cz * cz));
        d1 = (ia1 >= N) ? 3.4e38f : dist_fma(xq, yq, zq, sqq, cx, cy, cz, cw);
      }
      {
        int j_ = ia2 & (N - 1);
        float cx = sx[j_], cy = sy[j_], cz = sz[j_];
        float cw = fmaf(cx, cx, fmaf(cy, cy, cz * cz));
        d2 = (ia2 >= N) ? 3.4e38f : dist_fma(xq, yq, zq, sqq, cx, cy, cz, cw);
      }
      {
        int j_ = ia3 & (N - 1);
        float cx = sx[j_], cy = sy[j_], cz = sz[j_];
        float cw = fmaf(cx, cx, fmaf(cy, cy, cz * cz));
        d3 = (ia3 >= N) ? 3.4e38f : dist_fma(xq, yq, zq, sqq, cx, cy, cz, cw);
      }
      // group fast path: skip the whole insertion network if none qualify
      float mind = fminf(fminf(d0, d1), fminf(d2, d3));
      if (mind < kd[20]) {
        KNN_INSERT(d0, ia0);
        KNN_INSERT(d1, ia1);
        KNN_INSERT(d2, ia2);
        KNN_INSERT(d3, ia3);
      }
      ia0 = ib0; ia1 = ib1; ia2 = ib2; ia3 = ib3;
      ib0 = n0;  ib1 = n1;  ib2 = n2;  ib3 = n3;
    }
  }
  // wave1 parks its list; wave0 merges ascending (strict < keeps tie order)
  if (wv == 1) {
#pragma unroll
    for (int s = 0; s < 21; s++) { md[lane][s] = kd[s]; mi[lane][s] = ki[s]; }
  }
  __syncthreads();
  if (wv == 0) {
#pragma unroll
    for (int s = 0; s < 21; s++) {
      float dist = md[lane][s];
      int idx = mi[lane][s];
      KNN_INSERT(dist, idx);
    }
    int* nbq = nb + ((size_t)b * N + q) * NB_K;
#pragma unroll
    for (int tt = 0; tt < NB_K; tt++) nbq[tt] = ki[tt + 1];  // drop self (rank 0)
  }
}

// --- small-level knn (1024/256): proven two-pass chunked ladder ---
template <int N, int CHUNK, int NCH>
__global__ void k_knn_part(const float* __restrict__ v, int* __restrict__ part) {
  __shared__ float4 tile[CHUNK];
  int q = blockIdx.x * 64 + threadIdx.x;
  int ch = blockIdx.y;
  int b = blockIdx.z;
  const float* vb = v + (size_t)b * N * 3;
  int cbase = ch * CHUNK;
  for (int j = threadIdx.x; j < CHUNK; j += 64) {
    int g = cbase + j;
    float x = vb[g * 3 + 0], y = vb[g * 3 + 1], z = vb[g * 3 + 2];
    tile[j] = make_float4(x, y, z, fmaf(x, x, fmaf(y, y, z * z)));
  }
  __syncthreads();
  float xq = vb[q * 3 + 0], yq = vb[q * 3 + 1], zq = vb[q * 3 + 2];
  float sqq = fmaf(xq, xq, fmaf(yq, yq, zq * zq));
  float kd[21];
#pragma unroll
  for (int t = 0; t < 21; t++) kd[t] = 3.4e38f;
  for (int j = 0; j < CHUNK; j += 2) {
    float4 c0 = tile[j], c1 = tile[j + 1];
    float d0 = dist_fma(xq, yq, zq, sqq, c0.x, c0.y, c0.z, c0.w);
    float d1 = dist_fma(xq, yq, zq, sqq, c1.x, c1.y, c1.z, c1.w);
    float lo = fminf(d0, d1), hi = fmaxf(d0, d1);
#pragma unroll
    for (int t = 20; t >= 2; --t)
      kd[t] = fminf(fminf(kd[t], fmaxf(kd[t - 1], lo)), fmaxf(kd[t - 2], hi));
    kd[1] = fminf(fminf(kd[1], fmaxf(kd[0], lo)), hi);
    kd[0] = fminf(kd[0], lo);
  }
  float T = kd[20];
  int cnt = 0;
  int* pb = part + (((size_t)b * NCH + ch) * 21) * N + q;
  for (int j = 0; j < CHUNK; ++j) {
    float4 c = tile[j];
    float d = dist_fma(xq, yq, zq, sqq, c.x, c.y, c.z, c.w);
    if (d <= T && cnt < 21) { pb[(size_t)cnt * N] = cbase + j; cnt++; }
  }
}

// 2 waves per block (128 thr): wave h handles chunks [h*NCH/2, ...), same
// merge scheme as k_knn_merge2 (wave1 -> LDS -> wave0 inserts ascending).
template <int N, int NCH>
__global__ void k_knn_merge(const float* __restrict__ v, const int* __restrict__ part,
                            int* __restrict__ nb) {
  __shared__ float sx[N], sy[N], sz[N];   // N<=1024 -> <=12 KB
  __shared__ float md[64][21];
  __shared__ int   mi[64][21];
  int t = threadIdx.x;                    // 0..127
  int b = blockIdx.y;
  const float* vb = v + (size_t)b * N * 3;
  for (int j = t; j < N; j += 128) {
    sx[j] = vb[j * 3 + 0];
    sy[j] = vb[j * 3 + 1];
    sz[j] = vb[j * 3 + 2];
  }
  __syncthreads();
  int lane = t & 63;
  int wv = t >> 6;
  int q = blockIdx.x * 64 + lane;
  float xq = sx[q], yq = sy[q], zq = sz[q];
  float sqq = fmaf(xq, xq, fmaf(yq, yq, zq * zq));
  constexpr int HCH = NCH / 2;
  int ch0 = wv * HCH;
  float kd[21]; int ki[21];
#pragma unroll
  for (int t2 = 0; t2 < 21; t2++) { kd[t2] = 3.4e38f; ki[t2] = 0; }
#pragma unroll 1
  for (int cc = 0; cc < HCH; cc++) {
    int ch = ch0 + cc;
    // preload the whole chunk's 21 indices (independent loads, one latency)
    int idxs[21];
#pragma unroll
    for (int s = 0; s < 21; s++)
      idxs[s] = part[(((size_t)b * NCH + ch) * 21 + s) * N + q];
    // independent dist computations (LDS reads pipeline)
    float dsv[21];
#pragma unroll
    for (int s = 0; s < 21; s++) {
      int j_ = idxs[s];
      float cx = sx[j_], cy = sy[j_], cz = sz[j_];
      float cw = fmaf(cx, cx, fmaf(cy, cy, cz * cz));
      dsv[s] = dist_fma(xq, yq, zq, sqq, cx, cy, cz, cw);
    }
    // chunk fast path: skip whole insertion pass if none qualify
    float mn = dsv[0];
#pragma unroll
    for (int s = 1; s < 21; s++) mn = fminf(mn, dsv[s]);
    if (mn < kd[20]) {
#pragma unroll
      for (int s = 0; s < 21; s++) {
        float dist = dsv[s];
        int idx = idxs[s];
        KNN_INSERT(dist, idx);
      }
    }
  }
  if (wv == 1) {
#pragma unroll
    for (int s = 0; s < 21; s++) { md[lane][s] = kd[s]; mi[lane][s] = ki[s]; }
  }
  __syncthreads();
  if (wv == 0) {
#pragma unroll
    for (int s = 0; s < 21; s++) {
      float dist = md[lane][s];
      int idx = mi[lane][s];
      KNN_INSERT(dist, idx);
    }
    int* nbq = nb + ((size_t)b * N + q) * NB_K;
#pragma unroll
    for (int tt = 0; tt < NB_K; tt++) nbq[tt] = ki[tt + 1];
  }
}

// ---------------------------------------------------------------------------
// conv_surface
// ---------------------------------------------------------------------------
__global__ void k_surface(const float* __restrict__ v, const int* __restrict__ nb,
                          const float* __restrict__ dirn, float* __restrict__ out) {
  int idx = blockIdx.x * 64 + threadIdx.x;  // b*4096+n
  int b = idx >> 12, n = idx & 4095;
  const float* vb = v + (size_t)b * 4096 * 3;
  float xq = vb[n * 3 + 0], yq = vb[n * 3 + 1], zq = vb[n * 3 + 2];
  float mx[32];
#pragma unroll
  for (int f = 0; f < 32; f++) mx[f] = 0.0f;
  for (int k = 0; k < NB_K; k++) {
    int j = nb[(size_t)idx * NB_K + k];
    float dx = vb[j * 3 + 0] - xq, dy = vb[j * 3 + 1] - yq, dz = vb[j * 3 + 2] - zq;
    float nr = sqrtf((dx * dx + dy * dy) + dz * dz);
    float inv = 1.0f / fmaxf(nr, 1e-12f);
    dx *= inv; dy *= inv; dz *= inv;
#pragma unroll
    for (int f = 0; f < 32; f++) {
      float th = dx * dirn[f] + dy * dirn[32 + f] + dz * dirn[64 + f];
      th = fmaxf(th, 0.0f);
      mx[f] = fmaxf(mx[f], th);
    }
  }
#pragma unroll
  for (int f = 0; f < 32; f++) out[(size_t)idx * 32 + f] = mx[f];
}

// ---------------------------------------------------------------------------
// Tiled fp32 GEMM, BM=128 BN=64 BK=16, 256 thr, 8x4 per thread.
// Requires M%128==0, N%64==0, K%16==0. Accumulation: acc=bias then k
// ascending -- per-output-element fma chain identical to the 64x64 tile and
// to the reference matmul order (bitwise-stable across tile shapes).
// ---------------------------------------------------------------------------
__global__ void k_gemm_tile128(const float* __restrict__ A, const float* __restrict__ W,
                               const float* __restrict__ bias, float* __restrict__ out,
                               int M, int K, int N) {
  __shared__ float As[16][132];   // [k][m] row stride 528 B (16B-aligned reads)
  __shared__ float Bs[16][68];    // [k][n]
  int m0 = blockIdx.y * 128, n0 = blockIdx.x * 64;
  int t = threadIdx.x;
  int tr = t >> 4, tc = t & 15;       // compute: rows tr*8..+7, cols tc*4..+3
  int ar = t >> 2, ak4 = t & 3;       // A load: rows ar and ar+64, k-quad ak4
  int bk = t >> 4, bn4 = t & 15;      // B load: k-row bk, n-quad bn4
  float acc[8][4];
#pragma unroll
  for (int j = 0; j < 4; j++) {
    float bv = bias ? bias[n0 + tc * 4 + j] : 0.0f;
#pragma unroll
    for (int i = 0; i < 8; i++) acc[i][j] = bv;
  }
  for (int k0 = 0; k0 < K; k0 += 16) {
    float4 av0 = *(const float4*)(A + (size_t)(m0 + ar) * K + k0 + ak4 * 4);
    float4 av1 = *(const float4*)(A + (size_t)(m0 + ar + 64) * K + k0 + ak4 * 4);
    float4 wv  = *(const float4*)(W + (size_t)(k0 + bk) * N + n0 + bn4 * 4);
    __syncthreads();
    As[ak4 * 4 + 0][ar] = av0.x;
    As[ak4 * 4 + 1][ar] = av0.y;
    As[ak4 * 4 + 2][ar] = av0.z;
    As[ak4 * 4 + 3][ar] = av0.w;
    As[ak4 * 4 + 0][ar + 64] = av1.x;
    As[ak4 * 4 + 1][ar + 64] = av1.y;
    As[ak4 * 4 + 2][ar + 64] = av1.z;
    As[ak4 * 4 + 3][ar + 64] = av1.w;
    *(float4*)(&Bs[bk][bn4 * 4]) = wv;
    __syncthreads();
#pragma unroll
    for (int kk = 0; kk < 16; kk++) {
      float a[8], b[4];
#pragma unroll
      for (int i = 0; i < 8; i++) a[i] = As[kk][tr * 8 + i];
#pragma unroll
      for (int j = 0; j < 4; j++) b[j] = Bs[kk][tc * 4 + j];
#pragma unroll
      for (int i = 0; i < 8; i++)
#pragma unroll
        for (int j = 0; j < 4; j++) acc[i][j] = fmaf(a[i], b[j], acc[i][j]);
    }
  }
#pragma unroll
  for (int i = 0; i < 8; i++)
    *(float4*)(out + (size_t)(m0 + tr * 8 + i) * N + n0 + tc * 4) =
        make_float4(acc[i][0], acc[i][1], acc[i][2], acc[i][3]);
}

// 64x64 tile kept for the N=64 cluster GEMM (keeps 2x the blocks in flight).
__global__ void k_gemm_tile(const float* __restrict__ A, const float* __restrict__ W,
                            const float* __restrict__ bias, float* __restrict__ out,
                            int M, int K, int N) {
  __shared__ float As[16][68];
  __shared__ float Bs[16][68];
  int m0 = blockIdx.y * 64, n0 = blockIdx.x * 64;
  int t = threadIdx.x;
  int tr = t >> 4, tc = t & 15;
  int am = t >> 2, ak4 = t & 3;       // A load: row am, k-quad ak4
  int bk = t >> 4, bn4 = t & 15;      // B load: k-row bk, n-quad bn4
  float acc[4][4];
#pragma unroll
  for (int j = 0; j < 4; j++) {
    float bv = bias ? bias[n0 + tc * 4 + j] : 0.0f;
#pragma unroll
    for (int i = 0; i < 4; i++) acc[i][j] = bv;
  }
  for (int k0 = 0; k0 < K; k0 += 16) {
    float4 av = *(const float4*)(A + (size_t)(m0 + am) * K + k0 + ak4 * 4);
    float4 wv = *(const float4*)(W + (size_t)(k0 + bk) * N + n0 + bn4 * 4);
    __syncthreads();
    As[ak4 * 4 + 0][am] = av.x;
    As[ak4 * 4 + 1][am] = av.y;
    As[ak4 * 4 + 2][am] = av.z;
    As[ak4 * 4 + 3][am] = av.w;
    *(float4*)(&Bs[bk][bn4 * 4]) = wv;
    __syncthreads();
#pragma unroll
    for (int kk = 0; kk < 16; kk++) {
      float a[4], b[4];
#pragma unroll
      for (int i = 0; i < 4; i++) a[i] = As[kk][tr * 4 + i];
#pragma unroll
      for (int j = 0; j < 4; j++) b[j] = Bs[kk][tc * 4 + j];
#pragma unroll
      for (int i = 0; i < 4; i++)
#pragma unroll
        for (int j = 0; j < 4; j++) acc[i][j] = fmaf(a[i], b[j], acc[i][j]);
    }
  }
#pragma unroll
  for (int i = 0; i < 4; i++)
    *(float4*)(out + (size_t)(m0 + tr * 4 + i) * N + n0 + tc * 4) =
        make_float4(acc[i][0], acc[i][1], acc[i][2], acc[i][3]);
}

// small-M GEMM (gating, M=8)
template <int K>
__global__ void k_gemm4(const float* __restrict__ A, const float* __restrict__ W,
                        const float* __restrict__ bias, float* __restrict__ out,
                        int R, int C) {
  int idx = blockIdx.x * 256 + threadIdx.x;
  int c4 = C >> 2;
  if (idx >= R * c4) return;
  int r = idx / c4, c = (idx - r * c4) << 2;
  const float* a = A + (size_t)r * K;
  float4 acc;
  if (bias) acc = *(const float4*)(bias + c);
  else acc = make_float4(0.f, 0.f, 0.f, 0.f);
#pragma unroll 8
  for (int k = 0; k < K; k++) {
    float av = a[k];
    float4 wv = *(const float4*)(W + (size_t)k * C + c);
    acc.x = fmaf(av, wv.x, acc.x);
    acc.y = fmaf(av, wv.y, acc.y);
    acc.z = fmaf(av, wv.z, acc.z);
    acc.w = fmaf(av, wv.w, acc.w);
  }
  *(float4*)(out + (size_t)r * C + c) = acc;
}

// ---------------------------------------------------------------------------
// conv_layer combine
// ---------------------------------------------------------------------------
template <int COUT, int CPT, bool RELU>
__global__ void k_combine(const float* __restrict__ v, const int* __restrict__ nb,
                          const float* __restrict__ fo, const float* __restrict__ dirn,
                          float* __restrict__ out, int N) {
  constexpr int THREADS = COUT / CPT;
  int bn = blockIdx.x;
  int b = bn / N, n = bn - b * N;
  __shared__ float ds[NB_K][3];
  __shared__ int nbs[NB_K];
  const float* vb = v + (size_t)b * N * 3;
  if (threadIdx.x < NB_K) {
    int j = nb[(size_t)bn * NB_K + threadIdx.x];
    nbs[threadIdx.x] = j;
    float xq = vb[n * 3 + 0], yq = vb[n * 3 + 1], zq = vb[n * 3 + 2];
    float dx = vb[j * 3 + 0] - xq, dy = vb[j * 3 + 1] - yq, dz = vb[j * 3 + 2] - zq;
    float nr = sqrtf((dx * dx + dy * dy) + dz * dz);
    float inv = 1.0f / fmaxf(nr, 1e-12f);
    ds[threadIdx.x][0] = dx * inv;
    ds[threadIdx.x][1] = dy * inv;
    ds[threadIdx.x][2] = dz * inv;
  }
  __syncthreads();
#pragma unroll
  for (int cc = 0; cc < CPT; cc++) {
    int c = threadIdx.x + cc * THREADS;
    float w0 = dirn[c], w1 = dirn[COUT + c], w2 = dirn[2 * COUT + c];
    float acc = -3.4e38f;
    for (int k = 0; k < NB_K; k++) {
      float th = ds[k][0] * w0 + ds[k][1] * w1 + ds[k][2] * w2;
      th = fmaxf(th, 0.0f);
      float fs = fo[((size_t)b * N + nbs[k]) * (2 * COUT) + COUT + c];
      acc = fmaxf(acc, th * fs);
    }
    float res = fo[(size_t)bn * (2 * COUT) + c] + acc;
    if (RELU) res = fmaxf(res, 0.0f);
    out[(size_t)bn * COUT + c] = res;
  }
}

// ---------------------------------------------------------------------------
// gather-max pooling over neighbors
// ---------------------------------------------------------------------------
template <int C>
__global__ void k_gathermax(const float* __restrict__ fm, const int* __restrict__ nb,
                            float* __restrict__ out, int N) {
  int bn = blockIdx.x;
  int b = bn / N;
  __shared__ int nbs[NB_K];
  if (threadIdx.x < NB_K) nbs[threadIdx.x] = nb[(size_t)bn * NB_K + threadIdx.x];
  __syncthreads();
  int c = threadIdx.x;
  float acc = -3.4e38f;
  for (int k = 0; k < NB_K; k++)
    acc = fmaxf(acc, fm[((size_t)b * N + nbs[k]) * C + c]);
  out[(size_t)bn * C + c] = acc;
}

// ---------------------------------------------------------------------------
// pool-index gather
// ---------------------------------------------------------------------------
__global__ void k_poolgather(const float* __restrict__ in, const int* __restrict__ pool,
                             float* __restrict__ out, int n_in, int n_out, int C) {
  int idx = blockIdx.x * 256 + threadIdx.x;
  if (idx >= 8 * n_out * C) return;
  int c = idx % C; int t = idx / C; int i = t % n_out; int b = t / n_out;
  out[idx] = in[((size_t)b * n_in + pool[i]) * C + c];
}

// ---------------------------------------------------------------------------
// GeM pooling, n-split 4-way (32 -> 512 waves). Partial sums combined in
// fixed order ((p0+p1)+p2)+p3 -- deterministic, ~1e-7 rel vs serial order.
// ---------------------------------------------------------------------------
__global__ void k_gem(const float* __restrict__ fm4, const float* __restrict__ gp,
                      float* __restrict__ y) {
  __shared__ float red[4][64];
  int blk = blockIdx.x;            // 8*16 = 128 blocks
  int b = blk >> 4, f0 = (blk & 15) << 6;
  int fl = threadIdx.x & 63, ng = threadIdx.x >> 6;
  int f = f0 + fl;
  float p = gp[0];
  float s = 0.0f;
  const float* base = fm4 + (size_t)b * 256 * 1024 + f;
  if (p == 3.0f) {
    for (int n = ng * 64; n < ng * 64 + 64; n++) {
      float val = fmaxf(base[(size_t)n * 1024], 1e-6f);
      s += val * val * val;
    }
  } else {
    for (int n = ng * 64; n < ng * 64 + 64; n++) {
      float val = fmaxf(base[(size_t)n * 1024], 1e-6f);
      s += powf(val, p);
    }
  }
  red[ng][fl] = s;
  __syncthreads();
  if (ng == 0) {
    float st = ((red[0][fl] + red[1][fl]) + red[2][fl]) + red[3][fl];
    y[b * 1024 + f] = powf(st * (1.0f / 256.0f), 1.0f / p);
  }
}

// ---------------------------------------------------------------------------
// NetVLAD pieces
// ---------------------------------------------------------------------------
__global__ void k_bnstats(const float* __restrict__ x, int R, int C,
                          float* __restrict__ mean, float* __restrict__ rstd) {
  int c = blockIdx.x;
  __shared__ float red[256];
  float s = 0.0f;
  for (int r = threadIdx.x; r < R; r += 256) s += x[(size_t)r * C + c];
  red[threadIdx.x] = s; __syncthreads();
  for (int st = 128; st > 0; st >>= 1) {
    if (threadIdx.x < st) red[threadIdx.x] += red[threadIdx.x + st];
    __syncthreads();
  }
  float m = red[0] / (float)R;
  __syncthreads();
  float s2 = 0.0f;
  for (int r = threadIdx.x; r < R; r += 256) {
    float d = x[(size_t)r * C + c] - m; s2 += d * d;
  }
  red[threadIdx.x] = s2; __syncthreads();
  for (int st = 128; st > 0; st >>= 1) {
    if (threadIdx.x < st) red[threadIdx.x] += red[threadIdx.x + st];
    __syncthreads();
  }
  if (threadIdx.x == 0) {
    mean[c] = m;
    rstd[c] = 1.0f / sqrtf(red[0] / (float)R + BN_EPS);
  }
}

__global__ void k_softmax(const float* __restrict__ a0, const float* __restrict__ mean,
                          const float* __restrict__ rstd, const float* __restrict__ g,
                          const float* __restrict__ bb, float* __restrict__ act) {
  int r = blockIdx.x, c = threadIdx.x;
  float x = (a0[(size_t)r * 64 + c] - mean[c]) * rstd[c] * g[c] + bb[c];
  float mx = x;
  for (int off = 32; off > 0; off >>= 1) mx = fmaxf(mx, __shfl_xor(mx, off));
  float e = expf(x - mx);
  float sm = e;
  for (int off = 32; off > 0; off >>= 1) sm += __shfl_xor(sm, off);
  act[(size_t)r * 64 + c] = e / sm;
}

// m-split 4-way (8 -> 32 waves); ordered partial combine.
__global__ void k_colsum(const float* __restrict__ act, float* __restrict__ asum) {
  __shared__ float red[4][64];
  int b = blockIdx.x;
  int k = threadIdx.x & 63, mg = threadIdx.x >> 6;
  float s = 0.0f;
  for (int m = mg * 64; m < mg * 64 + 64; m++) s += act[((size_t)b * 256 + m) * 64 + k];
  red[mg][k] = s;
  __syncthreads();
  if (mg == 0)
    asum[b * 64 + k] = ((red[0][k] + red[1][k]) + red[2][k]) + red[3][k];
}

// vlad[b,f,k] = sum_m xv[b,m,f]*act[b,m,k] - asum[b,k]*cw2[f,k]
// tiled: block (f-tile 64 x k 64), LDS-staged, 4x4 per thread
__global__ void k_vlad_tile(const float* __restrict__ act, const float* __restrict__ xv,
                            const float* __restrict__ asum, const float* __restrict__ cw2,
                            float* __restrict__ vlad) {
  __shared__ float Xs[64][68];   // [m][f]
  __shared__ float Ac[64][68];   // [m][k]
  int b = blockIdx.y, f0 = blockIdx.x * 64;
  int t = threadIdx.x, tr = t >> 4, tc = t & 15;
  float acc[4][4] = {};
  for (int m0 = 0; m0 < 256; m0 += 64) {
    __syncthreads();
#pragma unroll
    for (int r = 0; r < 4; r++) {
      int m = r * 16 + (t >> 4);
      *(float4*)(&Xs[m][(t & 15) * 4]) =
          *(const float4*)(xv + ((size_t)b * 256 + m0 + m) * 1024 + f0 + (t & 15) * 4);
      *(float4*)(&Ac[m][(t & 15) * 4]) =
          *(const float4*)(act + ((size_t)b * 256 + m0 + m) * 64 + (t & 15) * 4);
    }
    __syncthreads();
    for (int mm = 0; mm < 64; mm++) {
      float a[4], c[4];
#pragma unroll
      for (int i = 0; i < 4; i++) a[i] = Xs[mm][tr * 4 + i];
#pragma unroll
      for (int j = 0; j < 4; j++) c[j] = Ac[mm][tc * 4 + j];
#pragma unroll
      for (int i = 0; i < 4; i++)
#pragma unroll
        for (int j = 0; j < 4; j++) acc[i][j] = fmaf(a[i], c[j], acc[i][j]);
    }
  }
#pragma unroll
  for (int i = 0; i < 4; i++) {
    int f = f0 + tr * 4 + i;
#pragma unroll
    for (int j = 0; j < 4; j++) {
      int k = tc * 4 + j;
      vlad[((size_t)b * 1024 + f) * 64 + k] = acc[i][j] - asum[b * 64 + k] * cw2[f * 64 + k];
    }
  }
}

__global__ void k_norm1(const float* __restrict__ vlad, float* __restrict__ scale1) {
  int bk = blockIdx.x;  // b*64+k
  int b = bk >> 6, k = bk & 63;
  float s = 0.0f;
  for (int f = threadIdx.x; f < 1024; f += 64) {
    float val = vlad[((size_t)b * 1024 + f) * 64 + k];
    s += val * val;
  }
  for (int off = 32; off > 0; off >>= 1) s += __shfl_xor(s, off);
  if (threadIdx.x == 0) scale1[bk] = 1.0f / fmaxf(sqrtf(s), 1e-12f);
}

__global__ void k_norm2(const float* __restrict__ vlad, const float* __restrict__ scale1,
                        float* __restrict__ scale2) {
  int b = blockIdx.x;
  __shared__ float red[256];
  float s = 0.0f;
  for (int i = threadIdx.x; i < 65536; i += 256) {
    float val = vlad[(size_t)b * 65536 + i] * scale1[b * 64 + (i & 63)];
    s += val * val;
  }
  red[threadIdx.x] = s; __syncthreads();
  for (int st = 128; st > 0; st >>= 1) {
    if (threadIdx.x < st) red[threadIdx.x] += red[threadIdx.x + st];
    __syncthreads();
  }
  if (threadIdx.x == 0) scale2[b] = 1.0f / fmaxf(sqrtf(red[0]), 1e-12f);
}

__global__ void k_vscale(float* __restrict__ vlad, const float* __restrict__ scale1,
                         const float* __restrict__ scale2) {
  int idx = blockIdx.x * 256 + threadIdx.x;
  int b = idx >> 16; int r = idx & 65535;
  vlad[idx] = vlad[idx] * scale1[b * 64 + (r & 63)] * scale2[b];
}

__global__ void k_hidden_partial(const float* __restrict__ vlad, const float* __restrict__ hw,
                                 float* __restrict__ partial) {
  __shared__ float vs[8][512];
  int cg = blockIdx.x;   // 0..3
  int kb = blockIdx.y;   // 0..127
  int col = cg * 256 + threadIdx.x;
  int k0 = kb * 512;
  for (int i = threadIdx.x; i < 8 * 512; i += 256) {
    int b = i >> 9, k = i & 511;
    vs[b][k] = vlad[(size_t)b * 65536 + k0 + k];
  }
  __syncthreads();
  float acc[8] = {0, 0, 0, 0, 0, 0, 0, 0};
  for (int k = 0; k < 512; k++) {
    float w = hw[(size_t)(k0 + k) * 1024 + col];
#pragma unroll
    for (int b = 0; b < 8; b++) acc[b] += vs[b][k] * w;
  }
#pragma unroll
  for (int b = 0; b < 8; b++)
    partial[((size_t)kb * 8 + b) * 1024 + col] = acc[b];
}

__global__ void k_hidden_reduce(const float* __restrict__ partial, float* __restrict__ hid) {
  int idx = blockIdx.x * 256 + threadIdx.x;  // b*1024+c
  int b = idx >> 10, c = idx & 1023;
  float s = 0.0f;
  for (int kb = 0; kb < 128; kb++) s += partial[((size_t)kb * 8 + b) * 1024 + c];
  hid[idx] = s;
}

__global__ void k_bn8(const float* __restrict__ x, const float* __restrict__ g,
                      const float* __restrict__ bb, float* __restrict__ out) {
  int c = blockIdx.x * 256 + threadIdx.x;
  if (c >= 1024) return;
  float v[8]; float s = 0.0f;
#pragma unroll
  for (int b = 0; b < 8; b++) { v[b] = x[b * 1024 + c]; s += v[b]; }
  float m = s * 0.125f; float s2 = 0.0f;
#pragma unroll
  for (int b = 0; b < 8; b++) { float d = v[b] - m; s2 += d * d; }
  float rstd = 1.0f / sqrtf(s2 * 0.125f + BN_EPS);
#pragma unroll
  for (int b = 0; b < 8; b++) out[b * 1024 + c] = (v[b] - m) * rstd * g[c] + bb[c];
}

__global__ void k_gbn_out(const float* __restrict__ gat, const float* __restrict__ g,
                          const float* __restrict__ bb, const float* __restrict__ vladbn,
                          float* __restrict__ desc) {
  int c = blockIdx.x * 256 + threadIdx.x;
  if (c >= 1024) return;
  float v[8]; float s = 0.0f;
#pragma unroll
  for (int b = 0; b < 8; b++) { v[b] = gat[b * 1024 + c]; s += v[b]; }
  float m = s * 0.125f; float s2 = 0.0f;
#pragma unroll
  for (int b = 0; b < 8; b++) { float d = v[b] - m; s2 += d * d; }
  float rstd = 1.0f / sqrtf(s2 * 0.125f + BN_EPS);
#pragma unroll
  for (int b = 0; b < 8; b++) {
    float x = (v[b] - m) * rstd * g[c] + bb[c];
    float gate = 1.0f / (1.0f + expf(-x));
    desc[b * 1024 + c] = vladbn[b * 1024 + c] * gate;
  }
}

// ---------------------------------------------------------------------------
// launch
// ---------------------------------------------------------------------------
extern "C" void kernel_launch(void* const* d_in, const int* in_sizes, int n_in,
                              void* d_out, int out_size, void* d_ws, size_t ws_size,
                              hipStream_t stream) {
  (void)in_sizes; (void)n_in; (void)out_size; (void)ws_size;
  const float* x    = (const float*)d_in[0];
  const float* dir0 = (const float*)d_in[1];
  const float* W1   = (const float*)d_in[2];
  const float* b1   = (const float*)d_in[3];
  const float* dir1 = (const float*)d_in[4];
  const float* W2   = (const float*)d_in[5];
  const float* b2   = (const float*)d_in[6];
  const float* dir2 = (const float*)d_in[7];
  const float* W3   = (const float*)d_in[8];
  const float* b3   = (const float*)d_in[9];
  const float* dir3 = (const float*)d_in[10];
  const float* W4   = (const float*)d_in[11];
  const float* b4   = (const float*)d_in[12];
  const float* dir4 = (const float*)d_in[13];
  const float* gemp = (const float*)d_in[14];
  const float* cw   = (const float*)d_in[15];
  const float* cw2  = (const float*)d_in[16];
  const float* hw   = (const float*)d_in[17];
  const float* bn1g = (const float*)d_in[18];
  const float* bn1b = (const float*)d_in[19];
  const float* bn2g = (const float*)d_in[20];
  const float* bn2b = (const float*)d_in[21];
  const float* gw   = (const float*)d_in[22];
  const float* gbng = (const float*)d_in[23];
  const float* gbnb = (const float*)d_in[24];
  float* out = (float*)d_out;
  char* ws = (char*)d_ws;

  float* F_DIRN0 = (float*)(ws + OFF_DIRN0);
  float* F_DIRN1 = (float*)(ws + OFF_DIRN1);
  float* F_DIRN2 = (float*)(ws + OFF_DIRN2);
  float* F_DIRN3 = (float*)(ws + OFF_DIRN3);
  float* F_DIRN4 = (float*)(ws + OFF_DIRN4);
  int*   I_POOL1 = (int*)(ws + OFF_POOL1);
  int*   I_POOL2 = (int*)(ws + OFF_POOL2);
  int*   I_NB    = (int*)(ws + OFF_NB);
  int*   I_KPART = (int*)(ws + OFF_KPART);
  unsigned short* U_KSURV = (unsigned short*)(ws + OFF_KSURV);
  int*   I_KCNT  = (int*)(ws + OFF_KCNT);
  float* F_KT0   = (float*)(ws + OFF_KT0);
  float* F_V2    = (float*)(ws + OFF_V2);
  float* F_V3    = (float*)(ws + OFF_V3);
  float* F_X1    = (float*)(ws + OFF_X1);
  float* F_X2    = (float*)(ws + OFF_X2);
  float* F_X3    = (float*)(ws + OFF_X3);
  float* F_X4    = (float*)(ws + OFF_X4);

  hipMemcpyAsync(I_POOL1, g_pools.p1, sizeof(g_pools.p1), hipMemcpyHostToDevice, stream);
  hipMemcpyAsync(I_POOL2, g_pools.p2, sizeof(g_pools.p2), hipMemcpyHostToDevice, stream);

  k_dirnorm<<<6, 256, 0, stream>>>(dir0, dir1, dir2, dir3, dir4,
                                   F_DIRN0, F_DIRN1, F_DIRN2, F_DIRN3, F_DIRN4);

  // ---- level 0: 4096 pts (sample -> filter -> merge) ----
  k_knn_sample<4096, 512><<<dim3(64, 8), 64, 0, stream>>>(x, F_KT0);
  k_knn_filter<4096, 512, 8, 64><<<dim3(64, 8, 8), 64, 0, stream>>>(x, F_KT0, U_KSURV, I_KCNT);
  k_knn_merge2<4096, 8, 64><<<dim3(64, 8), 128, 0, stream>>>(x, U_KSURV, I_KCNT, I_NB);
  k_surface<<<512, 64, 0, stream>>>(x, I_NB, F_DIRN0, F_X3);
  k_gemm_tile128<<<dim3(2, 256), 256, 0, stream>>>(F_X3, W1, b1, F_X1, 32768, 32, 128);
  k_combine<64, 1, true><<<32768, 64, 0, stream>>>(x, I_NB, F_X1, F_DIRN1, F_X4, 4096);
  k_gathermax<64><<<32768, 64, 0, stream>>>(F_X4, I_NB, F_X2, 4096);
  k_poolgather<<<(8 * 1024 * 3 + 255) / 256, 256, 0, stream>>>(x, I_POOL1, F_V2, 4096, 1024, 3);
  k_poolgather<<<(8 * 1024 * 64 + 255) / 256, 256, 0, stream>>>(F_X2, I_POOL1, F_X3, 4096, 1024, 64);

  // ---- level 1: 1024 pts ----
  k_knn_part<1024, 128, 8><<<dim3(16, 8, 8), 64, 0, stream>>>(F_V2, I_KPART);
  k_knn_merge<1024, 8><<<dim3(16, 8), 128, 0, stream>>>(F_V2, I_KPART, I_NB);
  k_gemm_tile128<<<dim3(4, 64), 256, 0, stream>>>(F_X3, W2, b2, F_X4, 8192, 64, 256);
  k_combine<128, 1, true><<<8192, 128, 0, stream>>>(F_V2, I_NB, F_X4, F_DIRN2, F_X1, 1024);
  k_gemm_tile128<<<dim3(8, 64), 256, 0, stream>>>(F_X1, W3, b3, F_X2, 8192, 128, 512);
  k_combine<256, 1, true><<<8192, 256, 0, stream>>>(F_V2, I_NB, F_X2, F_DIRN3, F_X4, 1024);
  k_gathermax<256><<<8192, 256, 0, stream>>>(F_X4, I_NB, F_X1, 1024);
  k_poolgather<<<(8 * 256 * 3 + 255) / 256, 256, 0, stream>>>(F_V2, I_POOL2, F_V3, 1024, 256, 3);
  k_poolgather<<<(8 * 256 * 256 + 255) / 256, 256, 0, stream>>>(F_X1, I_POOL2, F_X3, 1024, 256, 256);

  // ---- level 2: 256 pts ----
  k_knn_part<256, 64, 4><<<dim3(4, 4, 8), 64, 0, stream>>>(F_V3, I_KPART);
  k_knn_merge<256, 4><<<dim3(4, 8), 128, 0, stream>>>(F_V3, I_KPART, I_NB);
  k_gemm_tile128<<<dim3(32, 16), 256, 0, stream>>>(F_X3, W4, b4, F_X2, 2048, 256, 2048);
  k_combine<1024, 4, false><<<2048, 256, 0, stream>>>(F_V3, I_NB, F_X2, F_DIRN4, F_X4, 256);

  // ---- GeM head -> out[0:8192] ----
  k_gem<<<128, 256, 0, stream>>>(F_X4, gemp, out);

  // ---- NetVLAD head -> out[8192:16384] ----
  float* F_ACT0 = (float*)(ws + OFF_ACT0);
  float* F_ACT  = (float*)(ws + OFF_ACT);
  float* F_VLAD = (float*)(ws + OFF_VLAD);
  float* F_PART = (float*)(ws + OFF_PART);
  float* F_BN1M = (float*)(ws + OFF_BN1M);
  float* F_BN1R = (float*)(ws + OFF_BN1R);
  float* F_ASUM = (float*)(ws + OFF_ASUM);
  float* F_SC1  = (float*)(ws + OFF_SCALE1);
  float* F_SC2  = (float*)(ws + OFF_SCALE2);
  float* F_HID  = (float*)(ws + OFF_HID);
  float* F_VBN  = (float*)(ws + OFF_VLADBN);
  float* F_GAT  = (float*)(ws + OFF_GAT);

  k_gemm_tile<<<dim3(1, 32), 256, 0, stream>>>(F_X4, cw, nullptr, F_ACT0, 2048, 1024, 64);
  k_bnstats<<<64, 256, 0, stream>>>(F_ACT0, 2048, 64, F_BN1M, F_BN1R);
  k_softmax<<<2048, 64, 0, stream>>>(F_ACT0, F_BN1M, F_BN1R, bn1g, bn1b, F_ACT);
  k_colsum<<<8, 256, 0, stream>>>(F_ACT, F_ASUM);
  k_vlad_tile<<<dim3(16, 8), 256, 0, stream>>>(F_ACT, F_X4, F_ASUM, cw2, F_VLAD);
  k_norm1<<<512, 64, 0, stream>>>(F_VLAD, F_SC1);
  k_norm2<<<8, 256, 0, stream>>>(F_VLAD, F_SC1, F_SC2);
  k_vscale<<<(8 * 65536) / 256, 256, 0, stream>>>(F_VLAD, F_SC1, F_SC2);
  k_hidden_partial<<<dim3(4, 128), 256, 0, stream>>>(F_VLAD, hw, F_PART);
  k_hidden_reduce<<<32, 256, 0, stream>>>(F_PART, F_HID);
  k_bn8<<<4, 256, 0, stream>>>(F_HID, bn2g, bn2b, F_VBN);
  k_gemm4<1024><<<(8 * 256 + 255) / 256, 256, 0, stream>>>(F_VBN, gw, nullptr, F_GAT, 8, 1024);
  k_gbn_out<<<4, 256, 0, stream>>>(F_GAT, gbng, gbnb, F_VBN, out + 8192);
}